// Round 1
// baseline (6122.369 us; speedup 1.0000x reference)
//
#include <hip/hip_runtime.h>
#include <hip/hip_bf16.h>
#include <math.h>

typedef unsigned short u16;

#define HW 65536

__device__ __forceinline__ float bf2f(u16 u){
  union { unsigned int i; float f; } v; v.i = ((unsigned int)u) << 16; return v.f;
}
__device__ __forceinline__ u16 f2bf(float f){
  union { unsigned int i; float f; } v; v.f = f;
  unsigned int r = v.i + 0x7fffu + ((v.i >> 16) & 1u);
  return (u16)(r >> 16);
}
__device__ __forceinline__ float gelu_tanh(float v){
  float u = 0.7978845608028654f * (v + 0.044715f * v * v * v);
  float a = fabsf(u);
  float e = __expf(2.0f * a);
  float th = copysignf(1.0f - 2.0f / (e + 1.0f), u);
  return 0.5f * v * (1.0f + th);
}

// ---------------- Kernel 1: channel-LN + QKV 1x1 conv (GEMM 384x128) ----------------
__global__ __launch_bounds__(256) void k_ln_qkv(
    const float* __restrict__ x, const float* __restrict__ n1w,
    const float* __restrict__ n1b, const float* __restrict__ qkvw,
    const float* __restrict__ qkvb, u16* __restrict__ qkv)
{
  __shared__ float xs[128][64];
  __shared__ u16 wl[128][128];
  __shared__ float red[8][64];
  __shared__ float mu_s[64], rs_s[64];
  const int t = threadIdx.x;
  const int P0 = blockIdx.x * 64;
  const int b = P0 >> 16;
  const int pix0 = P0 & 65535;
  const float* xb = x + ((size_t)b * 128) * HW + pix0;

  for (int it = 0; it < 32; ++it){
    int idx = it * 256 + t;
    int c = idx >> 6, p = idx & 63;
    xs[c][p] = xb[(size_t)c * HW + p];
  }
  __syncthreads();
  {
    int part = t >> 6, p = t & 63;
    float s = 0.f, s2 = 0.f;
    #pragma unroll
    for (int i = 0; i < 32; ++i){ float v = xs[part*32 + i][p]; s += v; s2 += v*v; }
    red[part][p] = s; red[part + 4][p] = s2;
  }
  __syncthreads();
  if (t < 64){
    float s  = red[0][t] + red[1][t] + red[2][t] + red[3][t];
    float s2 = red[4][t] + red[5][t] + red[6][t] + red[7][t];
    float mu = s * 0.0078125f;
    float var = s2 * 0.0078125f - mu * mu;
    mu_s[t] = mu; rs_s[t] = rsqrtf(var + 1e-5f);
  }
  __syncthreads();
  for (int it = 0; it < 32; ++it){
    int idx = it * 256 + t;
    int c = idx >> 6, p = idx & 63;
    xs[c][p] = (xs[c][p] - mu_s[p]) * rs_s[p] * n1w[c] + n1b[c];
  }

  const int p0 = (t & 15) * 4;
  const int o0 = (t >> 4) * 8;
  for (int ob = 0; ob < 3; ++ob){
    __syncthreads();
    for (int it = 0; it < 64; ++it){
      int idx = it * 256 + t;
      int o = idx >> 7, c = idx & 127;
      wl[o][c] = f2bf(qkvw[(size_t)(ob * 128 + o) * 128 + c]);
    }
    __syncthreads();
    float acc[8][4];
    #pragma unroll
    for (int j = 0; j < 8; ++j)
      #pragma unroll
      for (int i = 0; i < 4; ++i) acc[j][i] = 0.f;
    #pragma unroll 4
    for (int c = 0; c < 128; ++c){
      float xv[4];
      #pragma unroll
      for (int i = 0; i < 4; ++i) xv[i] = xs[c][p0 + i];
      #pragma unroll
      for (int j = 0; j < 8; ++j){
        float wv = bf2f(wl[o0 + j][c]);
        #pragma unroll
        for (int i = 0; i < 4; ++i) acc[j][i] += wv * xv[i];
      }
    }
    #pragma unroll
    for (int j = 0; j < 8; ++j){
      int o = ob * 128 + o0 + j;
      float bb = qkvb[o];
      size_t base = ((size_t)b * 384 + o) * HW + pix0 + p0;
      #pragma unroll
      for (int i = 0; i < 4; ++i) qkv[base + i] = f2bf(acc[j][i] + bb);
    }
  }
}

// ---------------- Kernel 2: 7x7 local attention (zero-padded halo in LDS) ----------------
__global__ __launch_bounds__(256) void k_attn(const u16* __restrict__ qkv,
                                              u16* __restrict__ attn_out)
{
  __shared__ u16 kl[22 * 22 * 36];
  __shared__ u16 vl[22 * 22 * 36];
  const int t = threadIdx.x;
  const int blk = blockIdx.x;
  const int tx16 = blk & 15, ty16 = (blk >> 4) & 15;
  const int h = (blk >> 8) & 3, b = blk >> 10;
  const int y0 = ty16 * 16, x0 = tx16 * 16;
  const size_t kbase = ((size_t)b * 384 + 128 + h * 32) * HW;
  const size_t vbase = ((size_t)b * 384 + 256 + h * 32) * HW;

  for (int idx = t; idx < 484 * 32; idx += 256){
    int c = idx / 484;
    int pp = idx - c * 484;
    int yy = pp / 22;
    int xx = pp - yy * 22;
    int gy = y0 + yy - 3, gx = x0 + xx - 3;
    u16 kv = 0, vv = 0;
    if (gy >= 0 && gy < 256 && gx >= 0 && gx < 256){
      size_t off = (size_t)c * HW + gy * 256 + gx;
      kv = qkv[kbase + off];
      vv = qkv[vbase + off];
    }
    kl[pp * 36 + c] = kv;
    vl[pp * 36 + c] = vv;
  }
  __syncthreads();

  const int tx = t & 15, ty = t >> 4;
  const int gy = y0 + ty, gx = x0 + tx;
  const size_t qbase = ((size_t)b * 384 + h * 32) * HW + (size_t)gy * 256 + gx;
  float q[32];
  #pragma unroll
  for (int c = 0; c < 32; ++c) q[c] = bf2f(qkv[qbase + (size_t)c * HW]);

  float sc[49];
  #pragma unroll
  for (int o = 0; o < 49; ++o){
    const int oi = o / 7, oj = o % 7;
    const u16* kp = &kl[((ty + oi) * 22 + (tx + oj)) * 36];
    float s = 0.f;
    #pragma unroll
    for (int c = 0; c < 32; ++c) s += q[c] * bf2f(kp[c]);
    sc[o] = s * 0.17677669529663687f;
  }
  float m = sc[0];
  #pragma unroll
  for (int o = 1; o < 49; ++o) m = fmaxf(m, sc[o]);
  float sum = 0.f;
  #pragma unroll
  for (int o = 0; o < 49; ++o){ float e = __expf(sc[o] - m); sc[o] = e; sum += e; }
  const float inv = 1.f / sum;
  float acc[32];
  #pragma unroll
  for (int c = 0; c < 32; ++c) acc[c] = 0.f;
  #pragma unroll
  for (int o = 0; o < 49; ++o){
    const int oi = o / 7, oj = o % 7;
    const u16* vp = &vl[((ty + oi) * 22 + (tx + oj)) * 36];
    const float w = sc[o];
    #pragma unroll
    for (int c = 0; c < 32; ++c) acc[c] += w * bf2f(vp[c]);
  }
  const size_t obase = ((size_t)b * 128 + h * 32) * HW + (size_t)gy * 256 + gx;
  #pragma unroll
  for (int c = 0; c < 32; ++c) attn_out[obase + (size_t)c * HW] = f2bf(acc[c] * inv);
}

// ---------------- Kernel 3: proj 1x1 conv + residual -> y (d_out, fp32) ----------------
__global__ __launch_bounds__(256) void k_proj_res(
    const u16* __restrict__ attn, const float* __restrict__ projw,
    const float* __restrict__ projb, const float* __restrict__ x,
    float* __restrict__ y)
{
  __shared__ u16 al[128][64];
  __shared__ u16 wl[128][128];
  const int t = threadIdx.x;
  const int P0 = blockIdx.x * 64;
  const int b = P0 >> 16;
  const int pix0 = P0 & 65535;
  const u16* ab = attn + ((size_t)b * 128) * HW + pix0;
  for (int it = 0; it < 32; ++it){
    int idx = it * 256 + t;
    int c = idx >> 6, p = idx & 63;
    al[c][p] = ab[(size_t)c * HW + p];
  }
  for (int it = 0; it < 64; ++it){
    int idx = it * 256 + t;
    int o = idx >> 7, c = idx & 127;
    wl[o][c] = f2bf(projw[o * 128 + c]);
  }
  __syncthreads();
  const int p0 = (t & 15) * 4, o0 = (t >> 4) * 8;
  float acc[8][4];
  #pragma unroll
  for (int j = 0; j < 8; ++j)
    #pragma unroll
    for (int i = 0; i < 4; ++i) acc[j][i] = 0.f;
  #pragma unroll 4
  for (int c = 0; c < 128; ++c){
    float av[4];
    #pragma unroll
    for (int i = 0; i < 4; ++i) av[i] = bf2f(al[c][p0 + i]);
    #pragma unroll
    for (int j = 0; j < 8; ++j){
      float wv = bf2f(wl[o0 + j][c]);
      #pragma unroll
      for (int i = 0; i < 4; ++i) acc[j][i] += wv * av[i];
    }
  }
  #pragma unroll
  for (int j = 0; j < 8; ++j){
    int o = o0 + j;
    float bb = projb[o];
    size_t base = ((size_t)b * 128 + o) * HW + pix0 + p0;
    #pragma unroll
    for (int i = 0; i < 4; ++i) y[base + i] = x[base + i] + acc[j][i] + bb;
  }
}

// ---------------- Kernel 4: channel-LN2 + MLP (512 hidden, gelu-tanh) + residual ----------------
__global__ __launch_bounds__(256) void k_mlp(
    const float* __restrict__ yin, const float* __restrict__ n2w,
    const float* __restrict__ n2b, const float* __restrict__ w1,
    const float* __restrict__ b1, const float* __restrict__ w2,
    const float* __restrict__ b2, float* __restrict__ yout)
{
  __shared__ __align__(16) char smem[81920];
  float (*ys)[64] = (float(*)[64])smem;             // 32 KB
  u16 (*wl)[128]  = (u16(*)[128])(smem + 32768);    // 32 KB (w1 chunk then w2 chunk)
  u16 (*hl)[64]   = (u16(*)[64])(smem + 65536);     // 16 KB (h chunk, bf16)
  float* red  = (float*)(smem + 65536);             // aliased with hl (LN phase only)
  float* mu_s = (float*)(smem + 65536 + 2048);
  float* rs_s = (float*)(smem + 65536 + 2048 + 256);
  const int t = threadIdx.x;
  const int P0 = blockIdx.x * 64;
  const int b = P0 >> 16;
  const int pix0 = P0 & 65535;
  const float* yb = yin + ((size_t)b * 128) * HW + pix0;

  for (int it = 0; it < 32; ++it){
    int idx = it * 256 + t;
    int c = idx >> 6, p = idx & 63;
    ys[c][p] = yb[(size_t)c * HW + p];
  }
  __syncthreads();
  {
    int part = t >> 6, p = t & 63;
    float s = 0.f, s2 = 0.f;
    #pragma unroll
    for (int i = 0; i < 32; ++i){ float v = ys[part*32 + i][p]; s += v; s2 += v*v; }
    red[part * 64 + p] = s; red[(part + 4) * 64 + p] = s2;
  }
  __syncthreads();
  if (t < 64){
    float s  = red[0*64 + t] + red[1*64 + t] + red[2*64 + t] + red[3*64 + t];
    float s2 = red[4*64 + t] + red[5*64 + t] + red[6*64 + t] + red[7*64 + t];
    float mu = s * 0.0078125f;
    float var = s2 * 0.0078125f - mu * mu;
    mu_s[t] = mu; rs_s[t] = rsqrtf(var + 1e-5f);
  }
  __syncthreads();
  for (int it = 0; it < 32; ++it){
    int idx = it * 256 + t;
    int c = idx >> 6, p = idx & 63;
    ys[c][p] = (ys[c][p] - mu_s[p]) * rs_s[p] * n2w[c] + n2b[c];
  }

  const int p0 = (t & 15) * 4, o0 = (t >> 4) * 8;
  float acc2[8][4];
  #pragma unroll
  for (int j = 0; j < 8; ++j)
    #pragma unroll
    for (int i = 0; i < 4; ++i) acc2[j][i] = 0.f;

  for (int ch = 0; ch < 4; ++ch){
    __syncthreads();
    for (int it = 0; it < 64; ++it){
      int idx = it * 256 + t;
      int o = idx >> 7, c = idx & 127;
      wl[o][c] = f2bf(w1[(size_t)(ch * 128 + o) * 128 + c]);
    }
    __syncthreads();
    float ha[8][4];
    #pragma unroll
    for (int j = 0; j < 8; ++j)
      #pragma unroll
      for (int i = 0; i < 4; ++i) ha[j][i] = 0.f;
    #pragma unroll 4
    for (int c = 0; c < 128; ++c){
      float xv[4];
      #pragma unroll
      for (int i = 0; i < 4; ++i) xv[i] = ys[c][p0 + i];
      #pragma unroll
      for (int j = 0; j < 8; ++j){
        float wv = bf2f(wl[o0 + j][c]);
        #pragma unroll
        for (int i = 0; i < 4; ++i) ha[j][i] += wv * xv[i];
      }
    }
    #pragma unroll
    for (int j = 0; j < 8; ++j){
      float bb = b1[ch * 128 + o0 + j];
      #pragma unroll
      for (int i = 0; i < 4; ++i) hl[o0 + j][p0 + i] = f2bf(gelu_tanh(ha[j][i] + bb));
    }
    __syncthreads();
    for (int it = 0; it < 64; ++it){
      int idx = it * 256 + t;
      int o = idx >> 7, c = idx & 127;
      wl[o][c] = f2bf(w2[(size_t)o * 512 + ch * 128 + c]);
    }
    __syncthreads();
    #pragma unroll 4
    for (int c = 0; c < 128; ++c){
      float hv[4];
      #pragma unroll
      for (int i = 0; i < 4; ++i) hv[i] = bf2f(hl[c][p0 + i]);
      #pragma unroll
      for (int j = 0; j < 8; ++j){
        float wv = bf2f(wl[o0 + j][c]);
        #pragma unroll
        for (int i = 0; i < 4; ++i) acc2[j][i] += wv * hv[i];
      }
    }
  }
  #pragma unroll
  for (int j = 0; j < 8; ++j){
    int o = o0 + j;
    float bb = b2[o];
    size_t base = ((size_t)b * 128 + o) * HW + pix0 + p0;
    #pragma unroll
    for (int i = 0; i < 4; ++i) yout[base + i] = yin[base + i] + acc2[j][i] + bb;
  }
}

extern "C" void kernel_launch(void* const* d_in, const int* in_sizes, int n_in,
                              void* d_out, int out_size, void* d_ws, size_t ws_size,
                              hipStream_t stream)
{
  const float* x    = (const float*)d_in[0];
  const float* n1w  = (const float*)d_in[1];
  const float* n1b  = (const float*)d_in[2];
  const float* qkvw = (const float*)d_in[3];
  const float* qkvb = (const float*)d_in[4];
  const float* pw   = (const float*)d_in[5];
  const float* pb   = (const float*)d_in[6];
  const float* n2w  = (const float*)d_in[7];
  const float* n2b  = (const float*)d_in[8];
  const float* w1   = (const float*)d_in[9];
  const float* b1   = (const float*)d_in[10];
  const float* w2   = (const float*)d_in[11];
  const float* b2   = (const float*)d_in[12];

  u16* qkv  = (u16*)d_ws;                                  // 8*384*65536 bf16 = 384 MB
  u16* attn = (u16*)((char*)d_ws + 402653184ull);          // 8*128*65536 bf16 = 128 MB
  float* y  = (float*)d_out;

  k_ln_qkv<<<8192, 256, 0, stream>>>(x, n1w, n1b, qkvw, qkvb, qkv);
  k_attn<<<8192, 256, 0, stream>>>(qkv, attn);
  k_proj_res<<<8192, 256, 0, stream>>>(attn, pw, pb, x, y);
  k_mlp<<<8192, 256, 0, stream>>>(y, n2w, n2b, w1, b1, w2, b2, y);
}

// Round 2
// 1897.152 us; speedup vs baseline: 3.2271x; 3.2271x over previous
//
#include <hip/hip_runtime.h>
#include <hip/hip_bf16.h>

typedef unsigned short u16;
typedef unsigned int u32;
typedef __attribute__((ext_vector_type(4))) u32 u32x4;
typedef __attribute__((ext_vector_type(2))) u32 u32x2;
typedef __attribute__((ext_vector_type(8))) __bf16 bf16x8;
typedef __attribute__((ext_vector_type(4))) float f32x4;

#define HW 65536

__device__ __forceinline__ float bf2f(u16 u){
  union { u32 i; float f; } v; v.i = ((u32)u) << 16; return v.f;
}
__device__ __forceinline__ u16 f2bf(float f){
  union { u32 i; float f; } v; v.f = f;
  u32 r = v.i + 0x7fffu + ((v.i >> 16) & 1u);
  return (u16)(r >> 16);
}
__device__ __forceinline__ float bflo(u32 u){
  union { u32 i; float f; } v; v.i = u << 16; return v.f;
}
__device__ __forceinline__ float bfhi(u32 u){
  union { u32 i; float f; } v; v.i = u & 0xffff0000u; return v.f;
}
__device__ __forceinline__ float gelu_tanh(float v){
  float u = 0.7978845608028654f * (v + 0.044715f * v * v * v);
  float a = fabsf(u);
  float e = __expf(2.0f * a);
  float th = copysignf(1.0f - 2.0f / (e + 1.0f), u);
  return 0.5f * v * (1.0f + th);
}

// ---- pack weights (f32 [M][K]) into bf16 MFMA A-fragment tiles -------------
// tile (mt,kt): 1024 bf16, element (l,r) = W[mt*16 + (l&15)][kt*32 + 8*(l>>4) + r]
__global__ __launch_bounds__(256) void k_pack(
    const float* __restrict__ qkvw, const float* __restrict__ projw,
    const float* __restrict__ w1, const float* __restrict__ w2,
    u16* __restrict__ wf)
{
  int tile = blockIdx.x;
  const float* W; int K, KT, base, ti;
  if (tile < 96)       { W = qkvw; K = 128; KT = 4;  base = 0;      ti = tile; }
  else if (tile < 128) { W = projw; K = 128; KT = 4; base = 98304;  ti = tile - 96; }
  else if (tile < 256) { W = w1;   K = 128; KT = 4;  base = 131072; ti = tile - 128; }
  else                 { W = w2;   K = 512; KT = 16; base = 262144; ti = tile - 256; }
  int mt = ti / KT, kt = ti % KT;
  int t = threadIdx.x;
  int l = t >> 1, r0 = (t & 1) * 4;
  int m = mt * 16 + (l & 15);
  int kb = kt * 32 + 8 * (l >> 4) + r0;
  u16 o[4];
  #pragma unroll
  for (int j = 0; j < 4; ++j) o[j] = f2bf(W[(size_t)m * K + kb + j]);
  u32x2 v; v[0] = (u32)o[0] | ((u32)o[1] << 16); v[1] = (u32)o[2] | ((u32)o[3] << 16);
  *(u32x2*)(wf + base + ti * 1024 + l * 8 + r0) = v;
}

// ---- kernel 1: channel-LN + QKV GEMM (384x128), out bf16 [b][pix][384] -----
__global__ __launch_bounds__(256, 2) void k_ln_qkv(
    const float* __restrict__ x, const float* __restrict__ n1w,
    const float* __restrict__ n1b, const u16* __restrict__ wfq,
    const float* __restrict__ qkvb, u16* __restrict__ qkv)
{
  __shared__ __align__(16) char smem[66560];
  // xnT (swz) [64][128]bf16 @0 (16384); ys f32[128][64] @16384; outT [64][784B] @16384
  float (*ys)[64] = (float(*)[64])(smem + 16384);
  float* red  = (float*)(smem + 49152);
  float* mu_s = (float*)(smem + 51200);
  float* rs_s = (float*)(smem + 51456);

  const int t = threadIdx.x;
  const int P0 = blockIdx.x * 64;
  const int b = P0 >> 16;
  const int pix0 = P0 & 65535;
  const float* xb = x + ((size_t)b * 128) * HW + pix0;

  for (int it = 0; it < 32; ++it){
    int idx = it * 256 + t; int c = idx >> 6, p = idx & 63;
    ys[c][p] = xb[(size_t)c * HW + p];
  }
  __syncthreads();
  {
    int part = t >> 6, p = t & 63;
    float s = 0.f, s2 = 0.f;
    #pragma unroll
    for (int i = 0; i < 32; ++i){ float v = ys[part*32 + i][p]; s += v; s2 += v*v; }
    red[part * 64 + p] = s; red[(part + 4) * 64 + p] = s2;
  }
  __syncthreads();
  if (t < 64){
    float s  = red[0*64+t] + red[1*64+t] + red[2*64+t] + red[3*64+t];
    float s2 = red[4*64+t] + red[5*64+t] + red[6*64+t] + red[7*64+t];
    float mu = s * 0.0078125f;
    float var = s2 * 0.0078125f - mu * mu;
    mu_s[t] = mu; rs_s[t] = rsqrtf(var + 1e-5f);
  }
  __syncthreads();
  for (int it = 0; it < 4; ++it){
    int task = it * 256 + t;
    int p = task & 63, ch = task >> 6;
    int c0 = ch * 8;
    float mu = mu_s[p], rs = rs_s[p];
    u16 tmp[8];
    #pragma unroll
    for (int j = 0; j < 8; ++j){
      float v = (ys[c0 + j][p] - mu) * rs * n1w[c0 + j] + n1b[c0 + j];
      tmp[j] = f2bf(v);
    }
    u32x4 pk;
    pk[0] = (u32)tmp[0] | ((u32)tmp[1] << 16);
    pk[1] = (u32)tmp[2] | ((u32)tmp[3] << 16);
    pk[2] = (u32)tmp[4] | ((u32)tmp[5] << 16);
    pk[3] = (u32)tmp[6] | ((u32)tmp[7] << 16);
    *(u32x4*)(smem + p * 256 + ((ch ^ (p & 7)) << 4)) = pk;
  }
  __syncthreads();

  const int w = t >> 6, l = t & 63, lg = l >> 4, ln = l & 15;
  const bf16x8* wfrag = (const bf16x8*)wfq;
  f32x4 acc[6][4];
  #pragma unroll
  for (int m = 0; m < 6; ++m)
    #pragma unroll
    for (int n = 0; n < 4; ++n) acc[m][n] = (f32x4)(0.f);
  #pragma unroll
  for (int kt = 0; kt < 4; ++kt){
    bf16x8 a[6], bb[4];
    #pragma unroll
    for (int m = 0; m < 6; ++m) a[m] = wfrag[((w*6 + m)*4 + kt)*128 + l];
    #pragma unroll
    for (int n = 0; n < 4; ++n){
      int p = n * 16 + ln;
      bb[n] = *(const bf16x8*)(smem + p * 256 + ((((kt*4 + lg)) ^ (p & 7)) << 4));
    }
    #pragma unroll
    for (int m = 0; m < 6; ++m)
      #pragma unroll
      for (int n = 0; n < 4; ++n)
        acc[m][n] = __builtin_amdgcn_mfma_f32_16x16x32_bf16(a[m], bb[n], acc[m][n], 0, 0, 0);
  }
  #pragma unroll
  for (int m = 0; m < 6; ++m)
    #pragma unroll
    for (int n = 0; n < 4; ++n){
      int o0 = w * 96 + m * 16 + 4 * lg;
      int p = n * 16 + ln;
      u32x2 v;
      v[0] = (u32)f2bf(acc[m][n][0] + qkvb[o0+0]) | ((u32)f2bf(acc[m][n][1] + qkvb[o0+1]) << 16);
      v[1] = (u32)f2bf(acc[m][n][2] + qkvb[o0+2]) | ((u32)f2bf(acc[m][n][3] + qkvb[o0+3]) << 16);
      *(u32x2*)(smem + 16384 + p * 784 + o0 * 2) = v;
    }
  __syncthreads();
  for (int i = t; i < 3072; i += 256){
    int p = i / 48, ch = i - p * 48;
    u32x4 v = *(const u32x4*)(smem + 16384 + p * 784 + ch * 16);
    *(u32x4*)(qkv + ((size_t)(b * 65536 + pix0 + p) * 384 + ch * 8)) = v;
  }
}

// ---- kernel 2: 7x7 local attention; writes result into the q slots --------
__global__ __launch_bounds__(256, 2) void k_attn(u16* __restrict__ qkv)
{
  __shared__ u16 kl[484 * 40];
  __shared__ u16 vl[484 * 40];
  const int t = threadIdx.x;
  const int blk = blockIdx.x;
  const int tx16 = blk & 15, ty16 = (blk >> 4) & 15;
  const int h = (blk >> 8) & 3, b = blk >> 10;
  const int y0 = ty16 * 16, x0 = tx16 * 16;

  for (int i = t; i < 3872; i += 256){
    int pp = i >> 3, part = i & 7;
    int yy = pp / 22, xx = pp - yy * 22;
    int gy = y0 + yy - 3, gx = x0 + xx - 3;
    u32x4 val = {0u, 0u, 0u, 0u};
    if (gy >= 0 && gy < 256 && gx >= 0 && gx < 256){
      int sel = ((part < 4) ? 128 : 256) + h * 32 + (part & 3) * 8;
      val = *(const u32x4*)(qkv + ((size_t)(b * 65536 + gy * 256 + gx) * 384 + sel));
    }
    u16* dst = (part < 4 ? kl : vl) + pp * 40 + (part & 3) * 8;
    *(u32x4*)dst = val;
  }
  __syncthreads();

  const int tx = t & 15, ty = t >> 4;
  const int gy = y0 + ty, gx = x0 + tx;
  const int pix = gy * 256 + gx;
  u16* qp = qkv + (size_t)(b * 65536 + pix) * 384 + h * 32;
  float qf[32];
  #pragma unroll
  for (int j = 0; j < 4; ++j){
    u32x4 v = ((const u32x4*)qp)[j];
    #pragma unroll
    for (int w = 0; w < 4; ++w){
      qf[j*8 + w*2 + 0] = bflo(v[w]) * 0.17677669529663687f;
      qf[j*8 + w*2 + 1] = bfhi(v[w]) * 0.17677669529663687f;
    }
  }

  float sc[49];
  #pragma unroll
  for (int o = 0; o < 49; ++o){
    const int oi = o / 7, oj = o % 7;
    const u16* kp = kl + ((ty + oi) * 22 + (tx + oj)) * 40;
    float s = 0.f;
    #pragma unroll
    for (int j = 0; j < 4; ++j){
      u32x4 v = *(const u32x4*)(kp + j * 8);
      #pragma unroll
      for (int w = 0; w < 4; ++w){
        s += qf[j*8 + w*2 + 0] * bflo(v[w]);
        s += qf[j*8 + w*2 + 1] * bfhi(v[w]);
      }
    }
    sc[o] = s;
  }
  float m = sc[0];
  #pragma unroll
  for (int o = 1; o < 49; ++o) m = fmaxf(m, sc[o]);
  float sum = 0.f;
  #pragma unroll
  for (int o = 0; o < 49; ++o){ float e = __expf(sc[o] - m); sc[o] = e; sum += e; }
  const float inv = 1.f / sum;

  float acc[32];
  #pragma unroll
  for (int c = 0; c < 32; ++c) acc[c] = 0.f;
  #pragma unroll
  for (int o = 0; o < 49; ++o){
    const int oi = o / 7, oj = o % 7;
    const u16* vp = vl + ((ty + oi) * 22 + (tx + oj)) * 40;
    const float wgt = sc[o];
    #pragma unroll
    for (int j = 0; j < 4; ++j){
      u32x4 v = *(const u32x4*)(vp + j * 8);
      #pragma unroll
      for (int w = 0; w < 4; ++w){
        acc[j*8 + w*2 + 0] += wgt * bflo(v[w]);
        acc[j*8 + w*2 + 1] += wgt * bfhi(v[w]);
      }
    }
  }
  #pragma unroll
  for (int j = 0; j < 4; ++j){
    u32x4 v;
    #pragma unroll
    for (int w = 0; w < 4; ++w)
      v[w] = (u32)f2bf(acc[j*8 + w*2 + 0] * inv) | ((u32)f2bf(acc[j*8 + w*2 + 1] * inv) << 16);
    ((u32x4*)qp)[j] = v;
  }
}

// ---- kernel 3: proj GEMM (128x128) + residual -> y (f32, d_out) ------------
__global__ __launch_bounds__(256, 2) void k_proj_res(
    const u16* __restrict__ qkv, const u16* __restrict__ wfp,
    const float* __restrict__ projb, const float* __restrict__ x,
    float* __restrict__ y)
{
  __shared__ __align__(16) char smem[16384];
  const int t = threadIdx.x;
  const int P0 = blockIdx.x * 64;
  const int b = P0 >> 16;
  const int pix0 = P0 & 65535;

  for (int i = t; i < 1024; i += 256){
    int ch = i & 15, p = i >> 4;
    u32x4 v = *(const u32x4*)(qkv + ((size_t)(b * 65536 + pix0 + p) * 384 + ch * 8));
    *(u32x4*)(smem + p * 256 + ((ch ^ (p & 7)) << 4)) = v;
  }
  __syncthreads();

  const int w = t >> 6, l = t & 63, lg = l >> 4, ln = l & 15;
  const bf16x8* wfrag = (const bf16x8*)wfp;
  f32x4 acc[2][4];
  #pragma unroll
  for (int m = 0; m < 2; ++m)
    #pragma unroll
    for (int n = 0; n < 4; ++n) acc[m][n] = (f32x4)(0.f);
  #pragma unroll
  for (int kt = 0; kt < 4; ++kt){
    bf16x8 a[2], bb[4];
    #pragma unroll
    for (int m = 0; m < 2; ++m) a[m] = wfrag[((w*2 + m)*4 + kt)*128 + l];
    #pragma unroll
    for (int n = 0; n < 4; ++n){
      int p = n * 16 + ln;
      bb[n] = *(const bf16x8*)(smem + p * 256 + (((kt*4 + lg) ^ (p & 7)) << 4));
    }
    #pragma unroll
    for (int m = 0; m < 2; ++m)
      #pragma unroll
      for (int n = 0; n < 4; ++n)
        acc[m][n] = __builtin_amdgcn_mfma_f32_16x16x32_bf16(a[m], bb[n], acc[m][n], 0, 0, 0);
  }
  #pragma unroll
  for (int m = 0; m < 2; ++m)
    #pragma unroll
    for (int n = 0; n < 4; ++n){
      int o0 = w * 32 + m * 16 + 4 * lg;
      size_t base = ((size_t)(b * 128 + o0)) * HW + pix0 + n * 16 + ln;
      #pragma unroll
      for (int r = 0; r < 4; ++r)
        y[base + (size_t)r * HW] = x[base + (size_t)r * HW] + acc[m][n][r] + projb[o0 + r];
    }
}

// ---- kernel 4: channel-LN2 + MLP (two 256-h halves) + residual -------------
__global__ __launch_bounds__(256, 2) void k_mlp(
    const float* __restrict__ yin, const float* __restrict__ n2w,
    const float* __restrict__ n2b, const u16* __restrict__ wf1,
    const float* __restrict__ b1, const u16* __restrict__ wf2,
    const float* __restrict__ b2, float* __restrict__ yout)
{
  __shared__ __align__(16) char smem[51712];
  // xnT @0 (16384); hT/ys @16384 (32768); red @49152; mu @51200; rs @51456
  float (*ys)[64] = (float(*)[64])(smem + 16384);
  float* red  = (float*)(smem + 49152);
  float* mu_s = (float*)(smem + 51200);
  float* rs_s = (float*)(smem + 51456);

  const int t = threadIdx.x;
  const int P0 = blockIdx.x * 64;
  const int b = P0 >> 16;
  const int pix0 = P0 & 65535;
  const float* yb = yin + ((size_t)b * 128) * HW + pix0;

  for (int it = 0; it < 32; ++it){
    int idx = it * 256 + t; int c = idx >> 6, p = idx & 63;
    ys[c][p] = yb[(size_t)c * HW + p];
  }
  __syncthreads();
  {
    int part = t >> 6, p = t & 63;
    float s = 0.f, s2 = 0.f;
    #pragma unroll
    for (int i = 0; i < 32; ++i){ float v = ys[part*32 + i][p]; s += v; s2 += v*v; }
    red[part * 64 + p] = s; red[(part + 4) * 64 + p] = s2;
  }
  __syncthreads();
  if (t < 64){
    float s  = red[0*64+t] + red[1*64+t] + red[2*64+t] + red[3*64+t];
    float s2 = red[4*64+t] + red[5*64+t] + red[6*64+t] + red[7*64+t];
    float mu = s * 0.0078125f;
    float var = s2 * 0.0078125f - mu * mu;
    mu_s[t] = mu; rs_s[t] = rsqrtf(var + 1e-5f);
  }
  __syncthreads();
  for (int it = 0; it < 4; ++it){
    int task = it * 256 + t;
    int p = task & 63, ch = task >> 6;
    int c0 = ch * 8;
    float mu = mu_s[p], rs = rs_s[p];
    u16 tmp[8];
    #pragma unroll
    for (int j = 0; j < 8; ++j){
      float v = (ys[c0 + j][p] - mu) * rs * n2w[c0 + j] + n2b[c0 + j];
      tmp[j] = f2bf(v);
    }
    u32x4 pk;
    pk[0] = (u32)tmp[0] | ((u32)tmp[1] << 16);
    pk[1] = (u32)tmp[2] | ((u32)tmp[3] << 16);
    pk[2] = (u32)tmp[4] | ((u32)tmp[5] << 16);
    pk[3] = (u32)tmp[6] | ((u32)tmp[7] << 16);
    *(u32x4*)(smem + p * 256 + ((ch ^ (p & 7)) << 4)) = pk;
  }
  __syncthreads();

  const int w = t >> 6, l = t & 63, lg = l >> 4, ln = l & 15;
  const bf16x8* wf1f = (const bf16x8*)wf1;
  const bf16x8* wf2f = (const bf16x8*)wf2;
  f32x4 acc2[2][4];
  #pragma unroll
  for (int m = 0; m < 2; ++m)
    #pragma unroll
    for (int n = 0; n < 4; ++n) acc2[m][n] = (f32x4)(0.f);

  for (int half = 0; half < 2; ++half){
    if (half) __syncthreads();
    f32x4 acc1[4][4];
    #pragma unroll
    for (int m = 0; m < 4; ++m)
      #pragma unroll
      for (int n = 0; n < 4; ++n) acc1[m][n] = (f32x4)(0.f);
    #pragma unroll
    for (int kt = 0; kt < 4; ++kt){
      bf16x8 a[4], bb[4];
      #pragma unroll
      for (int m = 0; m < 4; ++m) a[m] = wf1f[((half*16 + w*4 + m)*4 + kt)*128 + l];
      #pragma unroll
      for (int n = 0; n < 4; ++n){
        int p = n * 16 + ln;
        bb[n] = *(const bf16x8*)(smem + p * 256 + (((kt*4 + lg) ^ (p & 7)) << 4));
      }
      #pragma unroll
      for (int m = 0; m < 4; ++m)
        #pragma unroll
        for (int n = 0; n < 4; ++n)
          acc1[m][n] = __builtin_amdgcn_mfma_f32_16x16x32_bf16(a[m], bb[n], acc1[m][n], 0, 0, 0);
    }
    #pragma unroll
    for (int m = 0; m < 4; ++m)
      #pragma unroll
      for (int n = 0; n < 4; ++n){
        int hrel = w * 64 + m * 16 + 4 * lg;
        int habs = half * 256 + hrel;
        int p = n * 16 + ln;
        float v0 = gelu_tanh(acc1[m][n][0] + b1[habs+0]);
        float v1 = gelu_tanh(acc1[m][n][1] + b1[habs+1]);
        float v2 = gelu_tanh(acc1[m][n][2] + b1[habs+2]);
        float v3 = gelu_tanh(acc1[m][n][3] + b1[habs+3]);
        u32x2 v;
        v[0] = (u32)f2bf(v0) | ((u32)f2bf(v1) << 16);
        v[1] = (u32)f2bf(v2) | ((u32)f2bf(v3) << 16);
        *(u32x2*)(smem + 16384 + p * 512 + ((((hrel >> 3) ^ (p & 7))) << 4) + ((hrel & 4) << 1)) = v;
      }
    __syncthreads();
    #pragma unroll
    for (int kt = 0; kt < 8; ++kt){
      bf16x8 a[2], bb[4];
      #pragma unroll
      for (int m = 0; m < 2; ++m) a[m] = wf2f[((w*2 + m)*16 + half*8 + kt)*128 + l];
      #pragma unroll
      for (int n = 0; n < 4; ++n){
        int p = n * 16 + ln;
        bb[n] = *(const bf16x8*)(smem + 16384 + p * 512 + (((kt*4 + lg) ^ (p & 7)) << 4));
      }
      #pragma unroll
      for (int m = 0; m < 2; ++m)
        #pragma unroll
        for (int n = 0; n < 4; ++n)
          acc2[m][n] = __builtin_amdgcn_mfma_f32_16x16x32_bf16(a[m], bb[n], acc2[m][n], 0, 0, 0);
    }
  }
  #pragma unroll
  for (int m = 0; m < 2; ++m)
    #pragma unroll
    for (int n = 0; n < 4; ++n){
      int o0 = w * 32 + m * 16 + 4 * lg;
      size_t base = ((size_t)(b * 128 + o0)) * HW + pix0 + n * 16 + ln;
      #pragma unroll
      for (int r = 0; r < 4; ++r)
        yout[base + (size_t)r * HW] = yin[base + (size_t)r * HW] + acc2[m][n][r] + b2[o0 + r];
    }
}

extern "C" void kernel_launch(void* const* d_in, const int* in_sizes, int n_in,
                              void* d_out, int out_size, void* d_ws, size_t ws_size,
                              hipStream_t stream)
{
  const float* x    = (const float*)d_in[0];
  const float* n1w  = (const float*)d_in[1];
  const float* n1b  = (const float*)d_in[2];
  const float* qkvw = (const float*)d_in[3];
  const float* qkvb = (const float*)d_in[4];
  const float* pw   = (const float*)d_in[5];
  const float* pb   = (const float*)d_in[6];
  const float* n2w  = (const float*)d_in[7];
  const float* n2b  = (const float*)d_in[8];
  const float* w1   = (const float*)d_in[9];
  const float* b1   = (const float*)d_in[10];
  const float* w2   = (const float*)d_in[11];
  const float* b2   = (const float*)d_in[12];

  u16* qkv = (u16*)d_ws;                                   // [8][65536][384] bf16 = 384 MB
  u16* wf  = (u16*)((char*)d_ws + 402653184ull);           // packed weights, 768 KB
  u16* wfq = wf;
  u16* wfp = wf + 98304;
  u16* wf1 = wf + 131072;
  u16* wf2 = wf + 262144;
  float* y = (float*)d_out;

  k_pack<<<384, 256, 0, stream>>>(qkvw, pw, w1, w2, wf);
  k_ln_qkv<<<8192, 256, 0, stream>>>(x, n1w, n1b, wfq, qkvb, qkv);
  k_attn<<<8192, 256, 0, stream>>>(qkv);
  k_proj_res<<<8192, 256, 0, stream>>>(qkv, wfp, pb, x, y);
  k_mlp<<<8192, 256, 0, stream>>>(y, n2w, n2b, wf1, b1, wf2, b2, y);
}

// Round 3
// 923.387 us; speedup vs baseline: 6.6303x; 2.0546x over previous
//
#include <hip/hip_runtime.h>
#include <hip/hip_bf16.h>

typedef unsigned short u16;
typedef unsigned int u32;
typedef __attribute__((ext_vector_type(4))) u32 u32x4;
typedef __attribute__((ext_vector_type(2))) u32 u32x2;
typedef __attribute__((ext_vector_type(8))) __bf16 bf16x8;
typedef __attribute__((ext_vector_type(4))) float f32x4;
typedef __attribute__((ext_vector_type(4))) short short4v;

#define HW 65536

__device__ __forceinline__ float bf2f(u16 u){
  union { u32 i; float f; } v; v.i = ((u32)u) << 16; return v.f;
}
__device__ __forceinline__ u16 f2bf(float f){
  union { u32 i; float f; } v; v.f = f;
  u32 r = v.i + 0x7fffu + ((v.i >> 16) & 1u);
  return (u16)(r >> 16);
}
__device__ __forceinline__ float gelu_tanh(float v){
  float u = 0.7978845608028654f * (v + 0.044715f * v * v * v);
  float a = fabsf(u);
  float e = __expf(2.0f * a);
  float th = copysignf(1.0f - 2.0f / (e + 1.0f), u);
  return 0.5f * v * (1.0f + th);
}

__device__ __forceinline__ f32x4 mfma16bf16(short4v a, short4v b, f32x4 c){
#if __has_builtin(__builtin_amdgcn_mfma_f32_16x16x16bf16_1k)
  return __builtin_amdgcn_mfma_f32_16x16x16bf16_1k(a, b, c, 0, 0, 0);
#else
  f32x4 d;
  asm volatile("v_mfma_f32_16x16x16_bf16 %0, %1, %2, %3"
               : "=v"(d) : "v"(a), "v"(b), "v"(c));
  return d;
#endif
}

// ---- pack weights (f32 [M][K]) into bf16 MFMA A-fragment tiles -------------
__global__ __launch_bounds__(256) void k_pack(
    const float* __restrict__ qkvw, const float* __restrict__ projw,
    const float* __restrict__ w1, const float* __restrict__ w2,
    u16* __restrict__ wf)
{
  int tile = blockIdx.x;
  const float* W; int K, KT, base, ti;
  if (tile < 96)       { W = qkvw; K = 128; KT = 4;  base = 0;      ti = tile; }
  else if (tile < 128) { W = projw; K = 128; KT = 4; base = 98304;  ti = tile - 96; }
  else if (tile < 256) { W = w1;   K = 128; KT = 4;  base = 131072; ti = tile - 128; }
  else                 { W = w2;   K = 512; KT = 16; base = 262144; ti = tile - 256; }
  int mt = ti / KT, kt = ti % KT;
  int t = threadIdx.x;
  int l = t >> 1, r0 = (t & 1) * 4;
  int m = mt * 16 + (l & 15);
  int kb = kt * 32 + 8 * (l >> 4) + r0;
  u16 o[4];
  #pragma unroll
  for (int j = 0; j < 4; ++j) o[j] = f2bf(W[(size_t)m * K + kb + j]);
  u32x2 v; v[0] = (u32)o[0] | ((u32)o[1] << 16); v[1] = (u32)o[2] | ((u32)o[3] << 16);
  *(u32x2*)(wf + base + ti * 1024 + l * 8 + r0) = v;
}

// ---- kernel 1: channel-LN + QKV GEMM; q/k/v planes [b][h][pix][32] bf16 ----
// q is pre-scaled by HEAD_DIM^-0.5.
__global__ __launch_bounds__(256, 2) void k_ln_qkv(
    const float* __restrict__ x, const float* __restrict__ n1w,
    const float* __restrict__ n1b, const u16* __restrict__ wfq,
    const float* __restrict__ qkvb, u16* __restrict__ qkvp)
{
  __shared__ __align__(16) char smem[66560];
  float (*ys)[64] = (float(*)[64])(smem + 16384);
  float* red  = (float*)(smem + 49152);
  float* mu_s = (float*)(smem + 51200);
  float* rs_s = (float*)(smem + 51456);

  const int t = threadIdx.x;
  const int P0 = blockIdx.x * 64;
  const int b = P0 >> 16;
  const int pix0 = P0 & 65535;
  const float* xb = x + ((size_t)b * 128) * HW + pix0;

  for (int it = 0; it < 32; ++it){
    int idx = it * 256 + t; int c = idx >> 6, p = idx & 63;
    ys[c][p] = xb[(size_t)c * HW + p];
  }
  __syncthreads();
  {
    int part = t >> 6, p = t & 63;
    float s = 0.f, s2 = 0.f;
    #pragma unroll
    for (int i = 0; i < 32; ++i){ float v = ys[part*32 + i][p]; s += v; s2 += v*v; }
    red[part * 64 + p] = s; red[(part + 4) * 64 + p] = s2;
  }
  __syncthreads();
  if (t < 64){
    float s  = red[0*64+t] + red[1*64+t] + red[2*64+t] + red[3*64+t];
    float s2 = red[4*64+t] + red[5*64+t] + red[6*64+t] + red[7*64+t];
    float mu = s * 0.0078125f;
    float var = s2 * 0.0078125f - mu * mu;
    mu_s[t] = mu; rs_s[t] = rsqrtf(var + 1e-5f);
  }
  __syncthreads();
  for (int it = 0; it < 4; ++it){
    int task = it * 256 + t;
    int p = task & 63, ch = task >> 6;
    int c0 = ch * 8;
    float mu = mu_s[p], rs = rs_s[p];
    u16 tmp[8];
    #pragma unroll
    for (int j = 0; j < 8; ++j){
      float v = (ys[c0 + j][p] - mu) * rs * n1w[c0 + j] + n1b[c0 + j];
      tmp[j] = f2bf(v);
    }
    u32x4 pk;
    pk[0] = (u32)tmp[0] | ((u32)tmp[1] << 16);
    pk[1] = (u32)tmp[2] | ((u32)tmp[3] << 16);
    pk[2] = (u32)tmp[4] | ((u32)tmp[5] << 16);
    pk[3] = (u32)tmp[6] | ((u32)tmp[7] << 16);
    *(u32x4*)(smem + p * 256 + ((ch ^ (p & 7)) << 4)) = pk;
  }
  __syncthreads();

  const int w = t >> 6, l = t & 63, lg = l >> 4, ln = l & 15;
  const bf16x8* wfrag = (const bf16x8*)wfq;
  f32x4 acc[6][4];
  #pragma unroll
  for (int m = 0; m < 6; ++m)
    #pragma unroll
    for (int n = 0; n < 4; ++n) acc[m][n] = (f32x4)(0.f);
  #pragma unroll
  for (int kt = 0; kt < 4; ++kt){
    bf16x8 a[6], bb[4];
    #pragma unroll
    for (int m = 0; m < 6; ++m) a[m] = wfrag[((w*6 + m)*4 + kt)*128 + l];
    #pragma unroll
    for (int n = 0; n < 4; ++n){
      int p = n * 16 + ln;
      bb[n] = *(const bf16x8*)(smem + p * 256 + ((((kt*4 + lg)) ^ (p & 7)) << 4));
    }
    #pragma unroll
    for (int m = 0; m < 6; ++m)
      #pragma unroll
      for (int n = 0; n < 4; ++n)
        acc[m][n] = __builtin_amdgcn_mfma_f32_16x16x32_bf16(a[m], bb[n], acc[m][n], 0, 0, 0);
  }
  #pragma unroll
  for (int m = 0; m < 6; ++m)
    #pragma unroll
    for (int n = 0; n < 4; ++n){
      int o0 = w * 96 + m * 16 + 4 * lg;
      float qs = (o0 < 128) ? 0.17677669529663687f : 1.0f;
      int p = n * 16 + ln;
      u32x2 v;
      v[0] = (u32)f2bf((acc[m][n][0] + qkvb[o0+0]) * qs) | ((u32)f2bf((acc[m][n][1] + qkvb[o0+1]) * qs) << 16);
      v[1] = (u32)f2bf((acc[m][n][2] + qkvb[o0+2]) * qs) | ((u32)f2bf((acc[m][n][3] + qkvb[o0+3]) * qs) << 16);
      *(u32x2*)(smem + 16384 + p * 784 + o0 * 2) = v;
    }
  __syncthreads();
  for (int i = t; i < 3072; i += 256){
    int p = i / 48, c8 = i - p * 48;
    u32x4 v = *(const u32x4*)(smem + 16384 + p * 784 + c8 * 16);
    int sel = c8 >> 4, hh = (c8 >> 2) & 3, c0 = (c8 & 3) * 8;
    u16* plane = qkvp + (size_t)sel * 67108864ull;
    *(u32x4*)(plane + (((size_t)(b*4 + hh)) * 65536 + pix0 + p) * 32 + c0) = v;
  }
}

// ---- kernel 2: 7x7 local attention via MFMA; writes over the q plane -------
__global__ __launch_bounds__(256, 2) void k_attn(
    u16* qbuf,                       // q plane, also output (same layout)
    const u16* __restrict__ kbuf, const u16* __restrict__ vbuf)
{
  __shared__ __align__(16) u16 Klds[4 * 512 * 8];     // [chgrp][pix512][8ch]
  __shared__ __align__(16) u16 VT[32 * 532 + 16];     // [ch][row22 x 24pad], zeroed
  const int t = threadIdx.x;
  const int blk = blockIdx.x;
  const int tx16 = blk & 15, ty16 = (blk >> 4) & 15;
  const int h = (blk >> 8) & 3, b = blk >> 10;
  const int y0 = ty16 * 16, x0 = tx16 * 16;
  const int bh = b * 4 + h;
  const u16* kg = kbuf + (size_t)bh * 65536 * 32;
  const u16* vg = vbuf + (size_t)bh * 65536 * 32;

  for (int i = t; i < 2130; i += 256) ((u32x4*)VT)[i] = (u32x4){0u,0u,0u,0u};
  __syncthreads();

  for (int pix = t; pix < 484; pix += 256){
    int yy = pix / 22, xx = pix - yy * 22;
    int gy = y0 + yy - 3, gx = x0 + xx - 3;
    bool ok = (gy >= 0 && gy < 256 && gx >= 0 && gx < 256);
    u32x4 kv[4], vv[4];
    #pragma unroll
    for (int j = 0; j < 4; ++j){ kv[j] = (u32x4){0u,0u,0u,0u}; vv[j] = (u32x4){0u,0u,0u,0u}; }
    if (ok){
      size_t gb = ((size_t)(gy * 256 + gx)) * 32;
      #pragma unroll
      for (int j = 0; j < 4; ++j){
        kv[j] = *(const u32x4*)(kg + gb + j * 8);
        vv[j] = *(const u32x4*)(vg + gb + j * 8);
      }
    }
    #pragma unroll
    for (int j = 0; j < 4; ++j)
      *(u32x4*)(Klds + (j * 512 + pix) * 8) = kv[j];
    int vb = yy * 24 + xx;
    #pragma unroll
    for (int j = 0; j < 4; ++j)
      #pragma unroll
      for (int ww = 0; ww < 4; ++ww){
        int c = j * 8 + ww * 2;
        VT[(c    ) * 532 + vb] = (u16)(vv[j][ww] & 0xffffu);
        VT[(c + 1) * 532 + vb] = (u16)(vv[j][ww] >> 16);
      }
  }
  __syncthreads();

  const int l = t & 63, w = t >> 6;
  const int ln = l & 15, g = l >> 4;

  bool mk[2][4];
  #pragma unroll
  for (int sl = 0; sl < 2; ++sl)
    #pragma unroll
    for (int r = 0; r < 4; ++r)
      mk[sl][r] = ((unsigned)(sl * 16 + g * 4 + r - ln)) <= 6u;

  for (int rt = 0; rt < 4; ++rt){
    int yl = rt * 4 + w;
    int qpix = (y0 + yl) * 256 + x0 + ln;
    u16* qp = qbuf + ((size_t)bh * 65536 + qpix) * 32;
    bf16x8 qf = *(const bf16x8*)(qp + g * 8);

    f32x4 S[7][2];
    #pragma unroll
    for (int oi = 0; oi < 7; ++oi){
      int rowb = (yl + oi) * 22;
      #pragma unroll
      for (int sl = 0; sl < 2; ++sl){
        bf16x8 kf = *(const bf16x8*)(Klds + (g * 512 + rowb + sl * 16 + ln) * 8);
        f32x4 z = (f32x4)(0.f);
        S[oi][sl] = __builtin_amdgcn_mfma_f32_16x16x32_bf16(kf, qf, z, 0, 0, 0);
      }
    }
    // banded softmax (per qp across 4 lanes l, l+16, l+32, l+48)
    float m = -3e38f;
    #pragma unroll
    for (int oi = 0; oi < 7; ++oi)
      #pragma unroll
      for (int sl = 0; sl < 2; ++sl)
        #pragma unroll
        for (int r = 0; r < 4; ++r){
          float v = mk[sl][r] ? S[oi][sl][r] : -3e38f;
          S[oi][sl][r] = v;
          m = fmaxf(m, v);
        }
    m = fmaxf(m, __shfl_xor(m, 16));
    m = fmaxf(m, __shfl_xor(m, 32));
    float sum = 0.f;
    #pragma unroll
    for (int oi = 0; oi < 7; ++oi)
      #pragma unroll
      for (int sl = 0; sl < 2; ++sl)
        #pragma unroll
        for (int r = 0; r < 4; ++r){
          float e = __expf(S[oi][sl][r] - m);
          S[oi][sl][r] = e;
          sum += e;
        }
    sum += __shfl_xor(sum, 16);
    sum += __shfl_xor(sum, 32);
    float inv = 1.f / sum;

    short4v P[7][2];
    #pragma unroll
    for (int oi = 0; oi < 7; ++oi)
      #pragma unroll
      for (int sl = 0; sl < 2; ++sl){
        union { u32x2 u; short4v s; } cv;
        cv.u[0] = (u32)f2bf(S[oi][sl][0]) | ((u32)f2bf(S[oi][sl][1]) << 16);
        cv.u[1] = (u32)f2bf(S[oi][sl][2]) | ((u32)f2bf(S[oi][sl][3]) << 16);
        P[oi][sl] = cv.s;
      }

    f32x4 O0 = (f32x4)(0.f), O1 = (f32x4)(0.f);
    #pragma unroll
    for (int oi = 0; oi < 7; ++oi){
      int rowE = (yl + oi) * 24;
      #pragma unroll
      for (int sl = 0; sl < 2; ++sl){
        int xb = rowE + sl * 16 + 4 * g;
        short4v v0 = *(const short4v*)(VT + (ln     ) * 532 + xb);
        short4v v1 = *(const short4v*)(VT + (ln + 16) * 532 + xb);
        O0 = mfma16bf16(v0, P[oi][sl], O0);
        O1 = mfma16bf16(v1, P[oi][sl], O1);
      }
    }
    // write out (in place over q): lane writes ch 4g..4g+3 (half0) and 16+4g.. (half1)
    union { u32x2 u; short4v s; } o0, o1;
    o0.u[0] = (u32)f2bf(O0[0]*inv) | ((u32)f2bf(O0[1]*inv) << 16);
    o0.u[1] = (u32)f2bf(O0[2]*inv) | ((u32)f2bf(O0[3]*inv) << 16);
    o1.u[0] = (u32)f2bf(O1[0]*inv) | ((u32)f2bf(O1[1]*inv) << 16);
    o1.u[1] = (u32)f2bf(O1[2]*inv) | ((u32)f2bf(O1[3]*inv) << 16);
    *(u32x2*)(qp + 4 * g)      = o0.u;
    *(u32x2*)(qp + 16 + 4 * g) = o1.u;
  }
}

// ---- kernel 3: proj GEMM (128x128) + residual -> y (f32, d_out) ------------
__global__ __launch_bounds__(256, 2) void k_proj_res(
    const u16* __restrict__ ao, const u16* __restrict__ wfp,
    const float* __restrict__ projb, const float* __restrict__ x,
    float* __restrict__ y)
{
  __shared__ __align__(16) char smem[16384];
  const int t = threadIdx.x;
  const int P0 = blockIdx.x * 64;
  const int b = P0 >> 16;
  const int pix0 = P0 & 65535;

  for (int i = t; i < 1024; i += 256){
    int ch = i & 15, p = i >> 4;
    int hh = ch >> 2, sub = (ch & 3) * 8;
    u32x4 v = *(const u32x4*)(ao + (((size_t)(b*4 + hh)) * 65536 + pix0 + p) * 32 + sub);
    *(u32x4*)(smem + p * 256 + ((ch ^ (p & 7)) << 4)) = v;
  }
  __syncthreads();

  const int w = t >> 6, l = t & 63, lg = l >> 4, ln = l & 15;
  const bf16x8* wfrag = (const bf16x8*)wfp;
  f32x4 acc[2][4];
  #pragma unroll
  for (int m = 0; m < 2; ++m)
    #pragma unroll
    for (int n = 0; n < 4; ++n) acc[m][n] = (f32x4)(0.f);
  #pragma unroll
  for (int kt = 0; kt < 4; ++kt){
    bf16x8 a[2], bb[4];
    #pragma unroll
    for (int m = 0; m < 2; ++m) a[m] = wfrag[((w*2 + m)*4 + kt)*128 + l];
    #pragma unroll
    for (int n = 0; n < 4; ++n){
      int p = n * 16 + ln;
      bb[n] = *(const bf16x8*)(smem + p * 256 + (((kt*4 + lg) ^ (p & 7)) << 4));
    }
    #pragma unroll
    for (int m = 0; m < 2; ++m)
      #pragma unroll
      for (int n = 0; n < 4; ++n)
        acc[m][n] = __builtin_amdgcn_mfma_f32_16x16x32_bf16(a[m], bb[n], acc[m][n], 0, 0, 0);
  }
  #pragma unroll
  for (int m = 0; m < 2; ++m)
    #pragma unroll
    for (int n = 0; n < 4; ++n){
      int o0 = w * 32 + m * 16 + 4 * lg;
      size_t base = ((size_t)(b * 128 + o0)) * HW + pix0 + n * 16 + ln;
      #pragma unroll
      for (int r = 0; r < 4; ++r)
        y[base + (size_t)r * HW] = x[base + (size_t)r * HW] + acc[m][n][r] + projb[o0 + r];
    }
}

// ---- kernel 4: channel-LN2 + MLP (two 256-h halves) + residual -------------
__global__ __launch_bounds__(256, 2) void k_mlp(
    const float* __restrict__ yin, const float* __restrict__ n2w,
    const float* __restrict__ n2b, const u16* __restrict__ wf1,
    const float* __restrict__ b1, const u16* __restrict__ wf2,
    const float* __restrict__ b2, float* __restrict__ yout)
{
  __shared__ __align__(16) char smem[51712];
  float (*ys)[64] = (float(*)[64])(smem + 16384);
  float* red  = (float*)(smem + 49152);
  float* mu_s = (float*)(smem + 51200);
  float* rs_s = (float*)(smem + 51456);

  const int t = threadIdx.x;
  const int P0 = blockIdx.x * 64;
  const int b = P0 >> 16;
  const int pix0 = P0 & 65535;
  const float* yb = yin + ((size_t)b * 128) * HW + pix0;

  for (int it = 0; it < 32; ++it){
    int idx = it * 256 + t; int c = idx >> 6, p = idx & 63;
    ys[c][p] = yb[(size_t)c * HW + p];
  }
  __syncthreads();
  {
    int part = t >> 6, p = t & 63;
    float s = 0.f, s2 = 0.f;
    #pragma unroll
    for (int i = 0; i < 32; ++i){ float v = ys[part*32 + i][p]; s += v; s2 += v*v; }
    red[part * 64 + p] = s; red[(part + 4) * 64 + p] = s2;
  }
  __syncthreads();
  if (t < 64){
    float s  = red[0*64+t] + red[1*64+t] + red[2*64+t] + red[3*64+t];
    float s2 = red[4*64+t] + red[5*64+t] + red[6*64+t] + red[7*64+t];
    float mu = s * 0.0078125f;
    float var = s2 * 0.0078125f - mu * mu;
    mu_s[t] = mu; rs_s[t] = rsqrtf(var + 1e-5f);
  }
  __syncthreads();
  for (int it = 0; it < 4; ++it){
    int task = it * 256 + t;
    int p = task & 63, ch = task >> 6;
    int c0 = ch * 8;
    float mu = mu_s[p], rs = rs_s[p];
    u16 tmp[8];
    #pragma unroll
    for (int j = 0; j < 8; ++j){
      float v = (ys[c0 + j][p] - mu) * rs * n2w[c0 + j] + n2b[c0 + j];
      tmp[j] = f2bf(v);
    }
    u32x4 pk;
    pk[0] = (u32)tmp[0] | ((u32)tmp[1] << 16);
    pk[1] = (u32)tmp[2] | ((u32)tmp[3] << 16);
    pk[2] = (u32)tmp[4] | ((u32)tmp[5] << 16);
    pk[3] = (u32)tmp[6] | ((u32)tmp[7] << 16);
    *(u32x4*)(smem + p * 256 + ((ch ^ (p & 7)) << 4)) = pk;
  }
  __syncthreads();

  const int w = t >> 6, l = t & 63, lg = l >> 4, ln = l & 15;
  const bf16x8* wf1f = (const bf16x8*)wf1;
  const bf16x8* wf2f = (const bf16x8*)wf2;
  f32x4 acc2[2][4];
  #pragma unroll
  for (int m = 0; m < 2; ++m)
    #pragma unroll
    for (int n = 0; n < 4; ++n) acc2[m][n] = (f32x4)(0.f);

  for (int half = 0; half < 2; ++half){
    if (half) __syncthreads();
    f32x4 acc1[4][4];
    #pragma unroll
    for (int m = 0; m < 4; ++m)
      #pragma unroll
      for (int n = 0; n < 4; ++n) acc1[m][n] = (f32x4)(0.f);
    #pragma unroll
    for (int kt = 0; kt < 4; ++kt){
      bf16x8 a[4], bb[4];
      #pragma unroll
      for (int m = 0; m < 4; ++m) a[m] = wf1f[((half*16 + w*4 + m)*4 + kt)*128 + l];
      #pragma unroll
      for (int n = 0; n < 4; ++n){
        int p = n * 16 + ln;
        bb[n] = *(const bf16x8*)(smem + p * 256 + (((kt*4 + lg) ^ (p & 7)) << 4));
      }
      #pragma unroll
      for (int m = 0; m < 4; ++m)
        #pragma unroll
        for (int n = 0; n < 4; ++n)
          acc1[m][n] = __builtin_amdgcn_mfma_f32_16x16x32_bf16(a[m], bb[n], acc1[m][n], 0, 0, 0);
    }
    #pragma unroll
    for (int m = 0; m < 4; ++m)
      #pragma unroll
      for (int n = 0; n < 4; ++n){
        int hrel = w * 64 + m * 16 + 4 * lg;
        int habs = half * 256 + hrel;
        int p = n * 16 + ln;
        float v0 = gelu_tanh(acc1[m][n][0] + b1[habs+0]);
        float v1 = gelu_tanh(acc1[m][n][1] + b1[habs+1]);
        float v2 = gelu_tanh(acc1[m][n][2] + b1[habs+2]);
        float v3 = gelu_tanh(acc1[m][n][3] + b1[habs+3]);
        u32x2 v;
        v[0] = (u32)f2bf(v0) | ((u32)f2bf(v1) << 16);
        v[1] = (u32)f2bf(v2) | ((u32)f2bf(v3) << 16);
        *(u32x2*)(smem + 16384 + p * 512 + ((((hrel >> 3) ^ (p & 7))) << 4) + ((hrel & 4) << 1)) = v;
      }
    __syncthreads();
    #pragma unroll
    for (int kt = 0; kt < 8; ++kt){
      bf16x8 a[2], bb[4];
      #pragma unroll
      for (int m = 0; m < 2; ++m) a[m] = wf2f[((w*2 + m)*16 + half*8 + kt)*128 + l];
      #pragma unroll
      for (int n = 0; n < 4; ++n){
        int p = n * 16 + ln;
        bb[n] = *(const bf16x8*)(smem + 16384 + p * 512 + (((kt*4 + lg) ^ (p & 7)) << 4));
      }
      #pragma unroll
      for (int m = 0; m < 2; ++m)
        #pragma unroll
        for (int n = 0; n < 4; ++n)
          acc2[m][n] = __builtin_amdgcn_mfma_f32_16x16x32_bf16(a[m], bb[n], acc2[m][n], 0, 0, 0);
    }
  }
  #pragma unroll
  for (int m = 0; m < 2; ++m)
    #pragma unroll
    for (int n = 0; n < 4; ++n){
      int o0 = w * 32 + m * 16 + 4 * lg;
      size_t base = ((size_t)(b * 128 + o0)) * HW + pix0 + n * 16 + ln;
      #pragma unroll
      for (int r = 0; r < 4; ++r)
        yout[base + (size_t)r * HW] = yin[base + (size_t)r * HW] + acc2[m][n][r] + b2[o0 + r];
    }
}

extern "C" void kernel_launch(void* const* d_in, const int* in_sizes, int n_in,
                              void* d_out, int out_size, void* d_ws, size_t ws_size,
                              hipStream_t stream)
{
  const float* x    = (const float*)d_in[0];
  const float* n1w  = (const float*)d_in[1];
  const float* n1b  = (const float*)d_in[2];
  const float* qkvw = (const float*)d_in[3];
  const float* qkvb = (const float*)d_in[4];
  const float* pw   = (const float*)d_in[5];
  const float* pb   = (const float*)d_in[6];
  const float* n2w  = (const float*)d_in[7];
  const float* n2b  = (const float*)d_in[8];
  const float* w1   = (const float*)d_in[9];
  const float* b1   = (const float*)d_in[10];
  const float* w2   = (const float*)d_in[11];
  const float* b2   = (const float*)d_in[12];

  u16* qkvp = (u16*)d_ws;                  // q/k/v planes, each [b][4][65536][32] = 128 MB
  u16* qbuf = qkvp;                        // q plane doubles as attention output
  u16* kbuf = qkvp + 67108864ull;
  u16* vbuf = qkvp + 134217728ull;
  u16* wf   = qkvp + 201326592ull;         // packed weights (768 KB) @ byte 384 MB
  u16* wfq = wf;
  u16* wfp = wf + 98304;
  u16* wf1 = wf + 131072;
  u16* wf2 = wf + 262144;
  float* y = (float*)d_out;

  k_pack<<<384, 256, 0, stream>>>(qkvw, pw, w1, w2, wf);
  k_ln_qkv<<<8192, 256, 0, stream>>>(x, n1w, n1b, wfq, qkvb, qkvp);
  k_attn<<<8192, 256, 0, stream>>>(qbuf, kbuf, vbuf);
  k_proj_res<<<8192, 256, 0, stream>>>(qbuf, wfp, pb, x, y);
  k_mlp<<<8192, 256, 0, stream>>>(y, n2w, n2b, wf1, b1, wf2, b2, y);
}

// Round 4
// 869.758 us; speedup vs baseline: 7.0392x; 1.0617x over previous
//
#include <hip/hip_runtime.h>
#include <hip/hip_bf16.h>

typedef unsigned short u16;
typedef unsigned int u32;
typedef __attribute__((ext_vector_type(4))) u32 u32x4;
typedef __attribute__((ext_vector_type(2))) u32 u32x2;
typedef __attribute__((ext_vector_type(8))) __bf16 bf16x8;
typedef __attribute__((ext_vector_type(4))) float f32x4;
typedef __attribute__((ext_vector_type(4))) short short4v;

#define HW 65536

__device__ __forceinline__ u16 f2bf(float f){
  union { u32 i; float f; } v; v.f = f;
  u32 r = v.i + 0x7fffu + ((v.i >> 16) & 1u);
  return (u16)(r >> 16);
}
__device__ __forceinline__ u32 pkbf(float a, float b){
  __bf16 lo = (__bf16)a, hi = (__bf16)b;
  u16 ulo = __builtin_bit_cast(u16, lo);
  u16 uhi = __builtin_bit_cast(u16, hi);
  return (u32)ulo | ((u32)uhi << 16);
}
__device__ __forceinline__ float gelu_tanh(float v){
  float u = 0.7978845608028654f * (v + 0.044715f * v * v * v);
  float a = fabsf(u);
  float e = __expf(2.0f * a);
  float th = copysignf(1.0f - 2.0f / (e + 1.0f), u);
  return 0.5f * v * (1.0f + th);
}

__device__ __forceinline__ f32x4 mfma16bf16(short4v a, short4v b, f32x4 c){
#if __has_builtin(__builtin_amdgcn_mfma_f32_16x16x16bf16_1k)
  return __builtin_amdgcn_mfma_f32_16x16x16bf16_1k(a, b, c, 0, 0, 0);
#else
  f32x4 d;
  asm volatile("v_mfma_f32_16x16x16_bf16 %0, %1, %2, %3"
               : "=v"(d) : "v"(a), "v"(b), "v"(c));
  return d;
#endif
}

// ---- pack weights (f32 [M][K]) into bf16 MFMA A-fragment tiles -------------
__global__ __launch_bounds__(256) void k_pack(
    const float* __restrict__ qkvw, const float* __restrict__ projw,
    const float* __restrict__ w1, const float* __restrict__ w2,
    u16* __restrict__ wf)
{
  int tile = blockIdx.x;
  const float* W; int K, KT, base, ti;
  if (tile < 96)       { W = qkvw; K = 128; KT = 4;  base = 0;      ti = tile; }
  else if (tile < 128) { W = projw; K = 128; KT = 4; base = 98304;  ti = tile - 96; }
  else if (tile < 256) { W = w1;   K = 128; KT = 4;  base = 131072; ti = tile - 128; }
  else                 { W = w2;   K = 512; KT = 16; base = 262144; ti = tile - 256; }
  int mt = ti / KT, kt = ti % KT;
  int t = threadIdx.x;
  int l = t >> 1, r0 = (t & 1) * 4;
  int m = mt * 16 + (l & 15);
  int kb = kt * 32 + 8 * (l >> 4) + r0;
  u16 o[4];
  #pragma unroll
  for (int j = 0; j < 4; ++j) o[j] = f2bf(W[(size_t)m * K + kb + j]);
  u32x2 v; v[0] = (u32)o[0] | ((u32)o[1] << 16); v[1] = (u32)o[2] | ((u32)o[3] << 16);
  *(u32x2*)(wf + base + ti * 1024 + l * 8 + r0) = v;
}

// ---- kernel 1: channel-LN + QKV GEMM; q/k/v planes [b][h][pix][32] bf16 ----
__global__ __launch_bounds__(256, 2) void k_ln_qkv(
    const float* __restrict__ x, const float* __restrict__ n1w,
    const float* __restrict__ n1b, const u16* __restrict__ wfq,
    const float* __restrict__ qkvb, u16* __restrict__ qkvp)
{
  __shared__ __align__(16) char smem[66560];
  float (*ys)[64] = (float(*)[64])(smem + 16384);
  float* red  = (float*)(smem + 49152);
  float* mu_s = (float*)(smem + 51200);
  float* rs_s = (float*)(smem + 51456);

  const int t = threadIdx.x;
  const int P0 = blockIdx.x * 64;
  const int b = P0 >> 16;
  const int pix0 = P0 & 65535;
  const float* xb = x + ((size_t)b * 128) * HW + pix0;

  for (int it = 0; it < 32; ++it){
    int idx = it * 256 + t; int c = idx >> 6, p = idx & 63;
    ys[c][p] = xb[(size_t)c * HW + p];
  }
  __syncthreads();
  {
    int part = t >> 6, p = t & 63;
    float s = 0.f, s2 = 0.f;
    #pragma unroll
    for (int i = 0; i < 32; ++i){ float v = ys[part*32 + i][p]; s += v; s2 += v*v; }
    red[part * 64 + p] = s; red[(part + 4) * 64 + p] = s2;
  }
  __syncthreads();
  if (t < 64){
    float s  = red[0*64+t] + red[1*64+t] + red[2*64+t] + red[3*64+t];
    float s2 = red[4*64+t] + red[5*64+t] + red[6*64+t] + red[7*64+t];
    float mu = s * 0.0078125f;
    float var = s2 * 0.0078125f - mu * mu;
    mu_s[t] = mu; rs_s[t] = rsqrtf(var + 1e-5f);
  }
  __syncthreads();
  for (int it = 0; it < 4; ++it){
    int task = it * 256 + t;
    int p = task & 63, ch = task >> 6;
    int c0 = ch * 8;
    float mu = mu_s[p], rs = rs_s[p];
    float vals[8];
    #pragma unroll
    for (int j = 0; j < 8; ++j)
      vals[j] = (ys[c0 + j][p] - mu) * rs * n1w[c0 + j] + n1b[c0 + j];
    u32x4 pk;
    pk[0] = pkbf(vals[0], vals[1]);
    pk[1] = pkbf(vals[2], vals[3]);
    pk[2] = pkbf(vals[4], vals[5]);
    pk[3] = pkbf(vals[6], vals[7]);
    *(u32x4*)(smem + p * 256 + ((ch ^ (p & 7)) << 4)) = pk;
  }
  __syncthreads();

  const int w = t >> 6, l = t & 63, lg = l >> 4, ln = l & 15;
  const bf16x8* wfrag = (const bf16x8*)wfq;
  f32x4 acc[6][4];
  #pragma unroll
  for (int m = 0; m < 6; ++m)
    #pragma unroll
    for (int n = 0; n < 4; ++n) acc[m][n] = (f32x4)(0.f);
  #pragma unroll
  for (int kt = 0; kt < 4; ++kt){
    bf16x8 a[6], bb[4];
    #pragma unroll
    for (int m = 0; m < 6; ++m) a[m] = wfrag[((w*6 + m)*4 + kt)*128 + l];
    #pragma unroll
    for (int n = 0; n < 4; ++n){
      int p = n * 16 + ln;
      bb[n] = *(const bf16x8*)(smem + p * 256 + ((((kt*4 + lg)) ^ (p & 7)) << 4));
    }
    #pragma unroll
    for (int m = 0; m < 6; ++m)
      #pragma unroll
      for (int n = 0; n < 4; ++n)
        acc[m][n] = __builtin_amdgcn_mfma_f32_16x16x32_bf16(a[m], bb[n], acc[m][n], 0, 0, 0);
  }
  #pragma unroll
  for (int m = 0; m < 6; ++m)
    #pragma unroll
    for (int n = 0; n < 4; ++n){
      int o0 = w * 96 + m * 16 + 4 * lg;
      float qs = (o0 < 128) ? 0.17677669529663687f : 1.0f;
      int p = n * 16 + ln;
      u32x2 v;
      v[0] = pkbf((acc[m][n][0] + qkvb[o0+0]) * qs, (acc[m][n][1] + qkvb[o0+1]) * qs);
      v[1] = pkbf((acc[m][n][2] + qkvb[o0+2]) * qs, (acc[m][n][3] + qkvb[o0+3]) * qs);
      *(u32x2*)(smem + 16384 + p * 784 + o0 * 2) = v;
    }
  __syncthreads();
  for (int i = t; i < 3072; i += 256){
    int p = i / 48, c8 = i - p * 48;
    u32x4 v = *(const u32x4*)(smem + 16384 + p * 784 + c8 * 16);
    int sel = c8 >> 4, hh = (c8 >> 2) & 3, c0 = (c8 & 3) * 8;
    u16* plane = qkvp + (size_t)sel * 67108864ull;
    *(u32x4*)(plane + (((size_t)(b*4 + hh)) * 65536 + pix0 + p) * 32 + c0) = v;
  }
}

// ---- kernel 2: 7x7 local attention via MFMA; writes over the q plane -------
__global__ __launch_bounds__(256, 2) void k_attn(
    u16* qbuf, const u16* __restrict__ kbuf, const u16* __restrict__ vbuf)
{
  __shared__ __align__(16) u16 Klds[4 * 512 * 8];
  __shared__ __align__(16) u16 VT[32 * 532 + 16];
  const int t = threadIdx.x;
  const int blk = blockIdx.x;
  const int tx16 = blk & 15, ty16 = (blk >> 4) & 15;
  const int h = (blk >> 8) & 3, b = blk >> 10;
  const int y0 = ty16 * 16, x0 = tx16 * 16;
  const int bh = b * 4 + h;
  const u16* kg = kbuf + (size_t)bh * 65536 * 32;
  const u16* vg = vbuf + (size_t)bh * 65536 * 32;

  for (int i = t; i < 2130; i += 256) ((u32x4*)VT)[i] = (u32x4){0u,0u,0u,0u};
  __syncthreads();

  for (int pix = t; pix < 484; pix += 256){
    int yy = pix / 22, xx = pix - yy * 22;
    int gy = y0 + yy - 3, gx = x0 + xx - 3;
    bool ok = (gy >= 0 && gy < 256 && gx >= 0 && gx < 256);
    u32x4 kv[4], vv[4];
    #pragma unroll
    for (int j = 0; j < 4; ++j){ kv[j] = (u32x4){0u,0u,0u,0u}; vv[j] = (u32x4){0u,0u,0u,0u}; }
    if (ok){
      size_t gb = ((size_t)(gy * 256 + gx)) * 32;
      #pragma unroll
      for (int j = 0; j < 4; ++j){
        kv[j] = *(const u32x4*)(kg + gb + j * 8);
        vv[j] = *(const u32x4*)(vg + gb + j * 8);
      }
    }
    #pragma unroll
    for (int j = 0; j < 4; ++j)
      *(u32x4*)(Klds + (j * 512 + pix) * 8) = kv[j];
    int vb = yy * 24 + xx;
    #pragma unroll
    for (int j = 0; j < 4; ++j)
      #pragma unroll
      for (int ww = 0; ww < 4; ++ww){
        int c = j * 8 + ww * 2;
        VT[(c    ) * 532 + vb] = (u16)(vv[j][ww] & 0xffffu);
        VT[(c + 1) * 532 + vb] = (u16)(vv[j][ww] >> 16);
      }
  }
  __syncthreads();

  const int l = t & 63, w = t >> 6;
  const int ln = l & 15, g = l >> 4;

  bool mk[2][4];
  #pragma unroll
  for (int sl = 0; sl < 2; ++sl)
    #pragma unroll
    for (int r = 0; r < 4; ++r)
      mk[sl][r] = ((unsigned)(sl * 16 + g * 4 + r - ln)) <= 6u;

  for (int rt = 0; rt < 4; ++rt){
    int yl = rt * 4 + w;
    int qpix = (y0 + yl) * 256 + x0 + ln;
    u16* qp = qbuf + ((size_t)bh * 65536 + qpix) * 32;
    bf16x8 qf = *(const bf16x8*)(qp + g * 8);

    f32x4 S[7][2];
    #pragma unroll
    for (int oi = 0; oi < 7; ++oi){
      int rowb = (yl + oi) * 22;
      #pragma unroll
      for (int sl = 0; sl < 2; ++sl){
        bf16x8 kf = *(const bf16x8*)(Klds + (g * 512 + rowb + sl * 16 + ln) * 8);
        f32x4 z = (f32x4)(0.f);
        S[oi][sl] = __builtin_amdgcn_mfma_f32_16x16x32_bf16(kf, qf, z, 0, 0, 0);
      }
    }
    float m = -3e38f;
    #pragma unroll
    for (int oi = 0; oi < 7; ++oi)
      #pragma unroll
      for (int sl = 0; sl < 2; ++sl)
        #pragma unroll
        for (int r = 0; r < 4; ++r){
          float v = mk[sl][r] ? S[oi][sl][r] : -3e38f;
          S[oi][sl][r] = v;
          m = fmaxf(m, v);
        }
    m = fmaxf(m, __shfl_xor(m, 16));
    m = fmaxf(m, __shfl_xor(m, 32));
    float sum = 0.f;
    #pragma unroll
    for (int oi = 0; oi < 7; ++oi)
      #pragma unroll
      for (int sl = 0; sl < 2; ++sl)
        #pragma unroll
        for (int r = 0; r < 4; ++r){
          float e = __expf(S[oi][sl][r] - m);
          S[oi][sl][r] = e;
          sum += e;
        }
    sum += __shfl_xor(sum, 16);
    sum += __shfl_xor(sum, 32);
    float inv = 1.f / sum;

    short4v P[7][2];
    #pragma unroll
    for (int oi = 0; oi < 7; ++oi)
      #pragma unroll
      for (int sl = 0; sl < 2; ++sl){
        union { u32x2 u; short4v s; } cv;
        cv.u[0] = pkbf(S[oi][sl][0], S[oi][sl][1]);
        cv.u[1] = pkbf(S[oi][sl][2], S[oi][sl][3]);
        P[oi][sl] = cv.s;
      }

    f32x4 O0 = (f32x4)(0.f), O1 = (f32x4)(0.f);
    #pragma unroll
    for (int oi = 0; oi < 7; ++oi){
      int rowE = (yl + oi) * 24;
      #pragma unroll
      for (int sl = 0; sl < 2; ++sl){
        int xb = rowE + sl * 16 + 4 * g;
        short4v v0 = *(const short4v*)(VT + (ln     ) * 532 + xb);
        short4v v1 = *(const short4v*)(VT + (ln + 16) * 532 + xb);
        O0 = mfma16bf16(v0, P[oi][sl], O0);
        O1 = mfma16bf16(v1, P[oi][sl], O1);
      }
    }
    u32x2 o0, o1;
    o0[0] = pkbf(O0[0]*inv, O0[1]*inv);
    o0[1] = pkbf(O0[2]*inv, O0[3]*inv);
    o1[0] = pkbf(O1[0]*inv, O1[1]*inv);
    o1[1] = pkbf(O1[2]*inv, O1[3]*inv);
    *(u32x2*)(qp + 4 * g)      = o0;
    *(u32x2*)(qp + 16 + 4 * g) = o1;
  }
}

// ---- kernel 3: proj GEMM + residual + channel-LN2 + MLP + residual ---------
__global__ __launch_bounds__(256, 3) void k_proj_mlp(
    const u16* __restrict__ ao, const u16* __restrict__ wfp,
    const float* __restrict__ projb, const float* __restrict__ x,
    const float* __restrict__ n2w, const float* __restrict__ n2b,
    const u16* __restrict__ wf1, const float* __restrict__ b1,
    const u16* __restrict__ wf2, const float* __restrict__ b2,
    float* __restrict__ yout)
{
  __shared__ __align__(16) char smem[52736];
  // xn/attn swizzled tile @0 (16384); ys f32[128][66] @16384 (33792, aliased by h);
  // red @50176 (2048); mu @52224; rs @52480
  float (*ys)[66] = (float(*)[66])(smem + 16384);
  float* red  = (float*)(smem + 50176);
  float* mu_s = (float*)(smem + 52224);
  float* rs_s = (float*)(smem + 52480);

  const int t = threadIdx.x;
  const int P0 = blockIdx.x * 64;
  const int b = P0 >> 16;
  const int pix0 = P0 & 65535;

  // ---- load attention-out tile into swizzled B-frag layout @0
  for (int i = t; i < 1024; i += 256){
    int ch = i & 15, p = i >> 4;
    int hh = ch >> 2, sub = (ch & 3) * 8;
    u32x4 v = *(const u32x4*)(ao + (((size_t)(b*4 + hh)) * 65536 + pix0 + p) * 32 + sub);
    *(u32x4*)(smem + p * 256 + ((ch ^ (p & 7)) << 4)) = v;
  }
  __syncthreads();

  const int w = t >> 6, l = t & 63, lg = l >> 4, ln = l & 15;
  // ---- proj GEMM
  const bf16x8* wfrag = (const bf16x8*)wfp;
  f32x4 yv[2][4];
  #pragma unroll
  for (int m = 0; m < 2; ++m)
    #pragma unroll
    for (int n = 0; n < 4; ++n) yv[m][n] = (f32x4)(0.f);
  #pragma unroll
  for (int kt = 0; kt < 4; ++kt){
    bf16x8 a[2], bb[4];
    #pragma unroll
    for (int m = 0; m < 2; ++m) a[m] = wfrag[((w*2 + m)*4 + kt)*128 + l];
    #pragma unroll
    for (int n = 0; n < 4; ++n){
      int p = n * 16 + ln;
      bb[n] = *(const bf16x8*)(smem + p * 256 + (((kt*4 + lg) ^ (p & 7)) << 4));
    }
    #pragma unroll
    for (int m = 0; m < 2; ++m)
      #pragma unroll
      for (int n = 0; n < 4; ++n)
        yv[m][n] = __builtin_amdgcn_mfma_f32_16x16x32_bf16(a[m], bb[n], yv[m][n], 0, 0, 0);
  }
  // ---- add bias + x residual; keep y in regs AND stage into ys for LN
  #pragma unroll
  for (int m = 0; m < 2; ++m)
    #pragma unroll
    for (int n = 0; n < 4; ++n){
      int o0 = w * 32 + m * 16 + 4 * lg;
      int p = n * 16 + ln;
      size_t base = ((size_t)(b * 128 + o0)) * HW + pix0 + p;
      #pragma unroll
      for (int r = 0; r < 4; ++r){
        float val = x[base + (size_t)r * HW] + yv[m][n][r] + projb[o0 + r];
        yv[m][n][r] = val;
        ys[o0 + r][p] = val;
      }
    }
  __syncthreads();
  // ---- LN stats
  {
    int part = t >> 6, p = t & 63;
    float s = 0.f, s2 = 0.f;
    #pragma unroll
    for (int i = 0; i < 32; ++i){ float v = ys[part*32 + i][p]; s += v; s2 += v*v; }
    red[part * 64 + p] = s; red[(part + 4) * 64 + p] = s2;
  }
  __syncthreads();
  if (t < 64){
    float s  = red[0*64+t] + red[1*64+t] + red[2*64+t] + red[3*64+t];
    float s2 = red[4*64+t] + red[5*64+t] + red[6*64+t] + red[7*64+t];
    float mu = s * 0.0078125f;
    float var = s2 * 0.0078125f - mu * mu;
    mu_s[t] = mu; rs_s[t] = rsqrtf(var + 1e-5f);
  }
  __syncthreads();
  // ---- normalize + pack into @0 (attn tile is dead now)
  for (int it = 0; it < 4; ++it){
    int task = it * 256 + t;
    int p = task & 63, ch = task >> 6;
    int c0 = ch * 8;
    float mu = mu_s[p], rs = rs_s[p];
    float vals[8];
    #pragma unroll
    for (int j = 0; j < 8; ++j)
      vals[j] = (ys[c0 + j][p] - mu) * rs * n2w[c0 + j] + n2b[c0 + j];
    u32x4 pk;
    pk[0] = pkbf(vals[0], vals[1]);
    pk[1] = pkbf(vals[2], vals[3]);
    pk[2] = pkbf(vals[4], vals[5]);
    pk[3] = pkbf(vals[6], vals[7]);
    *(u32x4*)(smem + p * 256 + ((ch ^ (p & 7)) << 4)) = pk;
  }
  __syncthreads();

  // ---- MLP (two 256-h halves); h aliases ys region
  const bf16x8* wf1f = (const bf16x8*)wf1;
  const bf16x8* wf2f = (const bf16x8*)wf2;
  f32x4 acc2[2][4];
  #pragma unroll
  for (int m = 0; m < 2; ++m)
    #pragma unroll
    for (int n = 0; n < 4; ++n) acc2[m][n] = (f32x4)(0.f);

  for (int half = 0; half < 2; ++half){
    if (half) __syncthreads();
    f32x4 acc1[4][4];
    #pragma unroll
    for (int m = 0; m < 4; ++m)
      #pragma unroll
      for (int n = 0; n < 4; ++n) acc1[m][n] = (f32x4)(0.f);
    #pragma unroll
    for (int kt = 0; kt < 4; ++kt){
      bf16x8 a[4], bb[4];
      #pragma unroll
      for (int m = 0; m < 4; ++m) a[m] = wf1f[((half*16 + w*4 + m)*4 + kt)*128 + l];
      #pragma unroll
      for (int n = 0; n < 4; ++n){
        int p = n * 16 + ln;
        bb[n] = *(const bf16x8*)(smem + p * 256 + (((kt*4 + lg) ^ (p & 7)) << 4));
      }
      #pragma unroll
      for (int m = 0; m < 4; ++m)
        #pragma unroll
        for (int n = 0; n < 4; ++n)
          acc1[m][n] = __builtin_amdgcn_mfma_f32_16x16x32_bf16(a[m], bb[n], acc1[m][n], 0, 0, 0);
    }
    #pragma unroll
    for (int m = 0; m < 4; ++m)
      #pragma unroll
      for (int n = 0; n < 4; ++n){
        int hrel = w * 64 + m * 16 + 4 * lg;
        int habs = half * 256 + hrel;
        int p = n * 16 + ln;
        float v0 = gelu_tanh(acc1[m][n][0] + b1[habs+0]);
        float v1 = gelu_tanh(acc1[m][n][1] + b1[habs+1]);
        float v2 = gelu_tanh(acc1[m][n][2] + b1[habs+2]);
        float v3 = gelu_tanh(acc1[m][n][3] + b1[habs+3]);
        u32x2 v;
        v[0] = pkbf(v0, v1);
        v[1] = pkbf(v2, v3);
        *(u32x2*)(smem + 16384 + p * 512 + ((((hrel >> 3) ^ (p & 7))) << 4) + ((hrel & 4) << 1)) = v;
      }
    __syncthreads();
    #pragma unroll
    for (int kt = 0; kt < 8; ++kt){
      bf16x8 a[2], bb[4];
      #pragma unroll
      for (int m = 0; m < 2; ++m) a[m] = wf2f[((w*2 + m)*16 + half*8 + kt)*128 + l];
      #pragma unroll
      for (int n = 0; n < 4; ++n){
        int p = n * 16 + ln;
        bb[n] = *(const bf16x8*)(smem + 16384 + p * 512 + (((kt*4 + lg) ^ (p & 7)) << 4));
      }
      #pragma unroll
      for (int m = 0; m < 2; ++m)
        #pragma unroll
        for (int n = 0; n < 4; ++n)
          acc2[m][n] = __builtin_amdgcn_mfma_f32_16x16x32_bf16(a[m], bb[n], acc2[m][n], 0, 0, 0);
    }
  }
  // ---- epilogue: out = y (regs) + mlp + b2
  #pragma unroll
  for (int m = 0; m < 2; ++m)
    #pragma unroll
    for (int n = 0; n < 4; ++n){
      int o0 = w * 32 + m * 16 + 4 * lg;
      size_t base = ((size_t)(b * 128 + o0)) * HW + pix0 + n * 16 + ln;
      #pragma unroll
      for (int r = 0; r < 4; ++r)
        yout[base + (size_t)r * HW] = yv[m][n][r] + acc2[m][n][r] + b2[o0 + r];
    }
}

extern "C" void kernel_launch(void* const* d_in, const int* in_sizes, int n_in,
                              void* d_out, int out_size, void* d_ws, size_t ws_size,
                              hipStream_t stream)
{
  const float* x    = (const float*)d_in[0];
  const float* n1w  = (const float*)d_in[1];
  const float* n1b  = (const float*)d_in[2];
  const float* qkvw = (const float*)d_in[3];
  const float* qkvb = (const float*)d_in[4];
  const float* pw   = (const float*)d_in[5];
  const float* pb   = (const float*)d_in[6];
  const float* n2w  = (const float*)d_in[7];
  const float* n2b  = (const float*)d_in[8];
  const float* w1   = (const float*)d_in[9];
  const float* b1   = (const float*)d_in[10];
  const float* w2   = (const float*)d_in[11];
  const float* b2   = (const float*)d_in[12];

  u16* qkvp = (u16*)d_ws;                  // q/k/v planes, each [b][4][65536][32] = 128 MB
  u16* qbuf = qkvp;                        // q plane doubles as attention output
  u16* kbuf = qkvp + 67108864ull;
  u16* vbuf = qkvp + 134217728ull;
  u16* wf   = qkvp + 201326592ull;         // packed weights (768 KB)
  u16* wfq = wf;
  u16* wfp = wf + 98304;
  u16* wf1 = wf + 131072;
  u16* wf2 = wf + 262144;
  float* y = (float*)d_out;

  k_pack<<<384, 256, 0, stream>>>(qkvw, pw, w1, w2, wf);
  k_ln_qkv<<<8192, 256, 0, stream>>>(x, n1w, n1b, wfq, qkvb, qkvp);
  k_attn<<<8192, 256, 0, stream>>>(qbuf, kbuf, vbuf);
  k_proj_mlp<<<8192, 256, 0, stream>>>(qbuf, wfp, pb, x, n2w, n2b, wf1, b1, wf2, b2, y);
}

// Round 5
// 840.525 us; speedup vs baseline: 7.2840x; 1.0348x over previous
//
#include <hip/hip_runtime.h>
#include <hip/hip_bf16.h>

typedef unsigned short u16;
typedef unsigned int u32;
typedef __attribute__((ext_vector_type(4))) u32 u32x4;
typedef __attribute__((ext_vector_type(2))) u32 u32x2;
typedef __attribute__((ext_vector_type(8))) __bf16 bf16x8;
typedef __attribute__((ext_vector_type(4))) float f32x4;
typedef __attribute__((ext_vector_type(4))) short short4v;

#define HW 65536

__device__ __forceinline__ u16 f2bf(float f){
  union { u32 i; float f; } v; v.f = f;
  u32 r = v.i + 0x7fffu + ((v.i >> 16) & 1u);
  return (u16)(r >> 16);
}
__device__ __forceinline__ u32 pkbf(float a, float b){
  __bf16 lo = (__bf16)a, hi = (__bf16)b;
  u16 ulo = __builtin_bit_cast(u16, lo);
  u16 uhi = __builtin_bit_cast(u16, hi);
  return (u32)ulo | ((u32)uhi << 16);
}
__device__ __forceinline__ float gelu_tanh(float v){
  float u = 0.7978845608028654f * (v + 0.044715f * v * v * v);
  float a = fabsf(u);
  float e = __expf(2.0f * a);
  float th = copysignf(1.0f - 2.0f / (e + 1.0f), u);
  return 0.5f * v * (1.0f + th);
}

__device__ __forceinline__ f32x4 mfma16bf16(short4v a, short4v b, f32x4 c){
#if __has_builtin(__builtin_amdgcn_mfma_f32_16x16x16bf16_1k)
  return __builtin_amdgcn_mfma_f32_16x16x16bf16_1k(a, b, c, 0, 0, 0);
#else
  f32x4 d;
  asm volatile("v_mfma_f32_16x16x16_bf16 %0, %1, %2, %3"
               : "=v"(d) : "v"(a), "v"(b), "v"(c));
  return d;
#endif
}

// ---- pack weights (f32 [M][K]) into bf16 MFMA A-fragment tiles -------------
__global__ __launch_bounds__(256) void k_pack(
    const float* __restrict__ qkvw, const float* __restrict__ projw,
    const float* __restrict__ w1, const float* __restrict__ w2,
    u16* __restrict__ wf)
{
  int tile = blockIdx.x;
  const float* W; int K, KT, base, ti;
  if (tile < 96)       { W = qkvw; K = 128; KT = 4;  base = 0;      ti = tile; }
  else if (tile < 128) { W = projw; K = 128; KT = 4; base = 98304;  ti = tile - 96; }
  else if (tile < 256) { W = w1;   K = 128; KT = 4;  base = 131072; ti = tile - 128; }
  else                 { W = w2;   K = 512; KT = 16; base = 262144; ti = tile - 256; }
  int mt = ti / KT, kt = ti % KT;
  int t = threadIdx.x;
  int l = t >> 1, r0 = (t & 1) * 4;
  int m = mt * 16 + (l & 15);
  int kb = kt * 32 + 8 * (l >> 4) + r0;
  u16 o[4];
  #pragma unroll
  for (int j = 0; j < 4; ++j) o[j] = f2bf(W[(size_t)m * K + kb + j]);
  u32x2 v; v[0] = (u32)o[0] | ((u32)o[1] << 16); v[1] = (u32)o[2] | ((u32)o[3] << 16);
  *(u32x2*)(wf + base + ti * 1024 + l * 8 + r0) = v;
}

// ---- kernel 1: channel-LN + QKV GEMM; q/k/v planes [b][h][pix][32] bf16 ----
// LN stats accumulate in registers during the global load (wave w owns
// channels w*32..w*32+31 for pixel = lane); x never round-trips LDS.
__global__ __launch_bounds__(256, 2) void k_ln_qkv(
    const float* __restrict__ x, const float* __restrict__ n1w,
    const float* __restrict__ n1b, const u16* __restrict__ wfq,
    const float* __restrict__ qkvb, u16* __restrict__ qkvp)
{
  __shared__ __align__(16) char smem[66560];
  // @0: xn B-frag 16 KB; @16384: red[512]f32 / mu[64] / rs[64] (aliased by out-stage)
  float* red  = (float*)(smem + 16384);
  float* mu_s = (float*)(smem + 18432);
  float* rs_s = (float*)(smem + 18688);

  const int t = threadIdx.x;
  const int w = t >> 6, l = t & 63;
  const int P0 = blockIdx.x * 64;
  const int b = P0 >> 16;
  const int pix0 = P0 & 65535;
  const float* xb = x + ((size_t)b * 128) * HW + pix0 + l;

  float xv[32];
  float s = 0.f, s2 = 0.f;
  #pragma unroll
  for (int j = 0; j < 32; ++j){
    float v = xb[(size_t)(w * 32 + j) * HW];
    xv[j] = v; s += v; s2 += v * v;
  }
  red[w * 64 + l] = s;
  red[256 + w * 64 + l] = s2;
  __syncthreads();
  if (t < 64){
    float ss  = red[t] + red[64 + t] + red[128 + t] + red[192 + t];
    float ss2 = red[256 + t] + red[320 + t] + red[384 + t] + red[448 + t];
    float mu = ss * 0.0078125f;
    float var = ss2 * 0.0078125f - mu * mu;
    mu_s[t] = mu; rs_s[t] = rsqrtf(var + 1e-5f);
  }
  __syncthreads();
  {
    float mu = mu_s[l], rs = rs_s[l];
    #pragma unroll
    for (int jj = 0; jj < 4; ++jj){
      int c0 = w * 32 + jj * 8;
      u32x4 pk;
      #pragma unroll
      for (int k2 = 0; k2 < 4; ++k2){
        float v0 = (xv[jj*8 + k2*2    ] - mu) * rs * n1w[c0 + k2*2    ] + n1b[c0 + k2*2    ];
        float v1 = (xv[jj*8 + k2*2 + 1] - mu) * rs * n1w[c0 + k2*2 + 1] + n1b[c0 + k2*2 + 1];
        pk[k2] = pkbf(v0, v1);
      }
      *(u32x4*)(smem + l * 256 + (((w * 4 + jj) ^ (l & 7)) << 4)) = pk;
    }
  }
  __syncthreads();

  const int lg = l >> 4, ln = l & 15;
  const bf16x8* wfrag = (const bf16x8*)wfq;
  f32x4 acc[6][4];
  #pragma unroll
  for (int m = 0; m < 6; ++m)
    #pragma unroll
    for (int n = 0; n < 4; ++n) acc[m][n] = (f32x4)(0.f);
  #pragma unroll
  for (int kt = 0; kt < 4; ++kt){
    bf16x8 a[6], bb[4];
    #pragma unroll
    for (int m = 0; m < 6; ++m) a[m] = wfrag[((w*6 + m)*4 + kt)*128 + l];
    #pragma unroll
    for (int n = 0; n < 4; ++n){
      int p = n * 16 + ln;
      bb[n] = *(const bf16x8*)(smem + p * 256 + ((((kt*4 + lg)) ^ (p & 7)) << 4));
    }
    #pragma unroll
    for (int m = 0; m < 6; ++m)
      #pragma unroll
      for (int n = 0; n < 4; ++n)
        acc[m][n] = __builtin_amdgcn_mfma_f32_16x16x32_bf16(a[m], bb[n], acc[m][n], 0, 0, 0);
  }
  #pragma unroll
  for (int m = 0; m < 6; ++m)
    #pragma unroll
    for (int n = 0; n < 4; ++n){
      int o0 = w * 96 + m * 16 + 4 * lg;
      float qs = (o0 < 128) ? 0.17677669529663687f : 1.0f;
      int p = n * 16 + ln;
      u32x2 v;
      v[0] = pkbf((acc[m][n][0] + qkvb[o0+0]) * qs, (acc[m][n][1] + qkvb[o0+1]) * qs);
      v[1] = pkbf((acc[m][n][2] + qkvb[o0+2]) * qs, (acc[m][n][3] + qkvb[o0+3]) * qs);
      *(u32x2*)(smem + 16384 + p * 784 + o0 * 2) = v;
    }
  __syncthreads();
  for (int i = t; i < 3072; i += 256){
    int p = i / 48, c8 = i - p * 48;
    u32x4 v = *(const u32x4*)(smem + 16384 + p * 784 + c8 * 16);
    int sel = c8 >> 4, hh = (c8 >> 2) & 3, c0 = (c8 & 3) * 8;
    u16* plane = qkvp + (size_t)sel * 67108864ull;
    *(u32x4*)(plane + (((size_t)(b*4 + hh)) * 65536 + pix0 + p) * 32 + c0) = v;
  }
}

// ---- kernel 2: 7x7 local attention via MFMA; writes over the q plane -------
__global__ __launch_bounds__(256, 2) void k_attn(
    u16* qbuf, const u16* __restrict__ kbuf, const u16* __restrict__ vbuf)
{
  __shared__ __align__(16) u16 Klds[4 * 512 * 8];
  __shared__ __align__(16) u16 VT[32 * 532 + 16];
  const int t = threadIdx.x;
  const int blk = blockIdx.x;
  const int tx16 = blk & 15, ty16 = (blk >> 4) & 15;
  const int h = (blk >> 8) & 3, b = blk >> 10;
  const int y0 = ty16 * 16, x0 = tx16 * 16;
  const int bh = b * 4 + h;
  const u16* kg = kbuf + (size_t)bh * 65536 * 32;
  const u16* vg = vbuf + (size_t)bh * 65536 * 32;

  for (int i = t; i < 2130; i += 256) ((u32x4*)VT)[i] = (u32x4){0u,0u,0u,0u};
  __syncthreads();

  for (int pix = t; pix < 484; pix += 256){
    int yy = pix / 22, xx = pix - yy * 22;
    int gy = y0 + yy - 3, gx = x0 + xx - 3;
    bool ok = (gy >= 0 && gy < 256 && gx >= 0 && gx < 256);
    u32x4 kv[4], vv[4];
    #pragma unroll
    for (int j = 0; j < 4; ++j){ kv[j] = (u32x4){0u,0u,0u,0u}; vv[j] = (u32x4){0u,0u,0u,0u}; }
    if (ok){
      size_t gb = ((size_t)(gy * 256 + gx)) * 32;
      #pragma unroll
      for (int j = 0; j < 4; ++j){
        kv[j] = *(const u32x4*)(kg + gb + j * 8);
        vv[j] = *(const u32x4*)(vg + gb + j * 8);
      }
    }
    #pragma unroll
    for (int j = 0; j < 4; ++j)
      *(u32x4*)(Klds + (j * 512 + pix) * 8) = kv[j];
    int vb = yy * 24 + xx;
    #pragma unroll
    for (int j = 0; j < 4; ++j)
      #pragma unroll
      for (int ww = 0; ww < 4; ++ww){
        int c = j * 8 + ww * 2;
        VT[(c    ) * 532 + vb] = (u16)(vv[j][ww] & 0xffffu);
        VT[(c + 1) * 532 + vb] = (u16)(vv[j][ww] >> 16);
      }
  }
  __syncthreads();

  const int l = t & 63, w = t >> 6;
  const int ln = l & 15, g = l >> 4;

  bool mk[2][4];
  #pragma unroll
  for (int sl = 0; sl < 2; ++sl)
    #pragma unroll
    for (int r = 0; r < 4; ++r)
      mk[sl][r] = ((unsigned)(sl * 16 + g * 4 + r - ln)) <= 6u;

  for (int rt = 0; rt < 4; ++rt){
    int yl = rt * 4 + w;
    int qpix = (y0 + yl) * 256 + x0 + ln;
    u16* qp = qbuf + ((size_t)bh * 65536 + qpix) * 32;
    bf16x8 qf = *(const bf16x8*)(qp + g * 8);

    f32x4 S[7][2];
    #pragma unroll
    for (int oi = 0; oi < 7; ++oi){
      int rowb = (yl + oi) * 22;
      #pragma unroll
      for (int sl = 0; sl < 2; ++sl){
        bf16x8 kf = *(const bf16x8*)(Klds + (g * 512 + rowb + sl * 16 + ln) * 8);
        f32x4 z = (f32x4)(0.f);
        S[oi][sl] = __builtin_amdgcn_mfma_f32_16x16x32_bf16(kf, qf, z, 0, 0, 0);
      }
    }
    float m = -3e38f;
    #pragma unroll
    for (int oi = 0; oi < 7; ++oi)
      #pragma unroll
      for (int sl = 0; sl < 2; ++sl)
        #pragma unroll
        for (int r = 0; r < 4; ++r){
          float v = mk[sl][r] ? S[oi][sl][r] : -3e38f;
          S[oi][sl][r] = v;
          m = fmaxf(m, v);
        }
    m = fmaxf(m, __shfl_xor(m, 16));
    m = fmaxf(m, __shfl_xor(m, 32));
    float sum = 0.f;
    #pragma unroll
    for (int oi = 0; oi < 7; ++oi)
      #pragma unroll
      for (int sl = 0; sl < 2; ++sl)
        #pragma unroll
        for (int r = 0; r < 4; ++r){
          float e = __expf(S[oi][sl][r] - m);
          S[oi][sl][r] = e;
          sum += e;
        }
    sum += __shfl_xor(sum, 16);
    sum += __shfl_xor(sum, 32);
    float inv = 1.f / sum;

    short4v P[7][2];
    #pragma unroll
    for (int oi = 0; oi < 7; ++oi)
      #pragma unroll
      for (int sl = 0; sl < 2; ++sl){
        union { u32x2 u; short4v s; } cv;
        cv.u[0] = pkbf(S[oi][sl][0], S[oi][sl][1]);
        cv.u[1] = pkbf(S[oi][sl][2], S[oi][sl][3]);
        P[oi][sl] = cv.s;
      }

    f32x4 O0 = (f32x4)(0.f), O1 = (f32x4)(0.f);
    #pragma unroll
    for (int oi = 0; oi < 7; ++oi){
      int rowE = (yl + oi) * 24;
      #pragma unroll
      for (int sl = 0; sl < 2; ++sl){
        int xb = rowE + sl * 16 + 4 * g;
        short4v v0 = *(const short4v*)(VT + (ln     ) * 532 + xb);
        short4v v1 = *(const short4v*)(VT + (ln + 16) * 532 + xb);
        O0 = mfma16bf16(v0, P[oi][sl], O0);
        O1 = mfma16bf16(v1, P[oi][sl], O1);
      }
    }
    u32x2 o0, o1;
    o0[0] = pkbf(O0[0]*inv, O0[1]*inv);
    o0[1] = pkbf(O0[2]*inv, O0[3]*inv);
    o1[0] = pkbf(O1[0]*inv, O1[1]*inv);
    o1[1] = pkbf(O1[2]*inv, O1[3]*inv);
    *(u32x2*)(qp + 4 * g)      = o0;
    *(u32x2*)(qp + 16 + 4 * g) = o1;
  }
}

// ---- kernel 3: proj GEMM + residual + reg-LN2 + MLP(quarters) + residual ---
__global__ __launch_bounds__(256, 4) void k_proj_mlp(
    const u16* __restrict__ ao, const u16* __restrict__ wfp,
    const float* __restrict__ projb, const float* __restrict__ x,
    const float* __restrict__ n2w, const float* __restrict__ n2b,
    const u16* __restrict__ wf1, const float* __restrict__ b1,
    const u16* __restrict__ wf2, const float* __restrict__ b2,
    float* __restrict__ yout)
{
  __shared__ __align__(16) char smem[35328];
  // @0: ao-frag then xn-frag (16 KB); @16384: h-frag (16 KB);
  // @32768: red[512] f32; @34816: mu[64]; @35072: rs[64]
  float* red  = (float*)(smem + 32768);
  float* mu_s = (float*)(smem + 34816);
  float* rs_s = (float*)(smem + 35072);

  const int t = threadIdx.x;
  const int P0 = blockIdx.x * 64;
  const int b = P0 >> 16;
  const int pix0 = P0 & 65535;

  for (int i = t; i < 1024; i += 256){
    int ch = i & 15, p = i >> 4;
    int hh = ch >> 2, sub = (ch & 3) * 8;
    u32x4 v = *(const u32x4*)(ao + (((size_t)(b*4 + hh)) * 65536 + pix0 + p) * 32 + sub);
    *(u32x4*)(smem + p * 256 + ((ch ^ (p & 7)) << 4)) = v;
  }
  __syncthreads();

  const int w = t >> 6, l = t & 63, lg = l >> 4, ln = l & 15;
  // ---- proj GEMM
  const bf16x8* wfrag = (const bf16x8*)wfp;
  f32x4 yv[2][4];
  #pragma unroll
  for (int m = 0; m < 2; ++m)
    #pragma unroll
    for (int n = 0; n < 4; ++n) yv[m][n] = (f32x4)(0.f);
  #pragma unroll
  for (int kt = 0; kt < 4; ++kt){
    bf16x8 a[2], bb[4];
    #pragma unroll
    for (int m = 0; m < 2; ++m) a[m] = wfrag[((w*2 + m)*4 + kt)*128 + l];
    #pragma unroll
    for (int n = 0; n < 4; ++n){
      int p = n * 16 + ln;
      bb[n] = *(const bf16x8*)(smem + p * 256 + (((kt*4 + lg) ^ (p & 7)) << 4));
    }
    #pragma unroll
    for (int m = 0; m < 2; ++m)
      #pragma unroll
      for (int n = 0; n < 4; ++n)
        yv[m][n] = __builtin_amdgcn_mfma_f32_16x16x32_bf16(a[m], bb[n], yv[m][n], 0, 0, 0);
  }
  // ---- bias + x residual (y stays in regs); per-pixel LN partials via shfl
  float sn[4], s2n[4];
  #pragma unroll
  for (int m = 0; m < 2; ++m){
    int o0 = w * 32 + m * 16 + 4 * lg;
    f32x4 pbv = *(const f32x4*)(projb + o0);
    #pragma unroll
    for (int n = 0; n < 4; ++n){
      size_t base = ((size_t)(b * 128 + o0)) * HW + pix0 + n * 16 + ln;
      if (m == 0){ sn[n] = 0.f; s2n[n] = 0.f; }
      #pragma unroll
      for (int r = 0; r < 4; ++r){
        float val = x[base + (size_t)r * HW] + yv[m][n][r] + pbv[r];
        yv[m][n][r] = val;
        sn[n] += val; s2n[n] += val * val;
      }
    }
  }
  #pragma unroll
  for (int n = 0; n < 4; ++n){
    sn[n]  += __shfl_xor(sn[n], 16);  sn[n]  += __shfl_xor(sn[n], 32);
    s2n[n] += __shfl_xor(s2n[n], 16); s2n[n] += __shfl_xor(s2n[n], 32);
  }
  {
    float ssel  = (lg & 1) ? ((lg & 2) ? sn[3]  : sn[1])  : ((lg & 2) ? sn[2]  : sn[0]);
    float s2sel = (lg & 1) ? ((lg & 2) ? s2n[3] : s2n[1]) : ((lg & 2) ? s2n[2] : s2n[0]);
    red[w * 64 + lg * 16 + ln] = ssel;
    red[256 + w * 64 + lg * 16 + ln] = s2sel;
  }
  __syncthreads();
  if (t < 64){
    float ss  = red[t] + red[64 + t] + red[128 + t] + red[192 + t];
    float ss2 = red[256 + t] + red[320 + t] + red[384 + t] + red[448 + t];
    float mu = ss * 0.0078125f;
    float var = ss2 * 0.0078125f - mu * mu;
    mu_s[t] = mu; rs_s[t] = rsqrtf(var + 1e-5f);
  }
  __syncthreads();
  // ---- normalize from regs -> xn-frag @0 (ao tile is dead)
  #pragma unroll
  for (int m = 0; m < 2; ++m){
    int c0 = w * 32 + m * 16 + 4 * lg;
    f32x4 wv = *(const f32x4*)(n2w + c0);
    f32x4 bv = *(const f32x4*)(n2b + c0);
    int g8 = w * 4 + m * 2 + (lg >> 1);
    #pragma unroll
    for (int n = 0; n < 4; ++n){
      int p = n * 16 + ln;
      float mu = mu_s[p], rs = rs_s[p];
      float x0 = (yv[m][n][0] - mu) * rs * wv[0] + bv[0];
      float x1 = (yv[m][n][1] - mu) * rs * wv[1] + bv[1];
      float x2 = (yv[m][n][2] - mu) * rs * wv[2] + bv[2];
      float x3 = (yv[m][n][3] - mu) * rs * wv[3] + bv[3];
      u32x2 pk; pk[0] = pkbf(x0, x1); pk[1] = pkbf(x2, x3);
      *(u32x2*)(smem + p * 256 + ((g8 ^ (p & 7)) << 4) + ((lg & 1) << 3)) = pk;
    }
  }
  __syncthreads();

  // ---- MLP in 4 quarters of 128 hidden rows; h-frag @16384
  const bf16x8* wf1f = (const bf16x8*)wf1;
  const bf16x8* wf2f = (const bf16x8*)wf2;
  f32x4 acc2[2][4];
  #pragma unroll
  for (int m = 0; m < 2; ++m)
    #pragma unroll
    for (int n = 0; n < 4; ++n) acc2[m][n] = (f32x4)(0.f);

  for (int q = 0; q < 4; ++q){
    // W1 quarter (rows q*128..q*128+127), n-split to cap registers
    #pragma unroll
    for (int nh = 0; nh < 2; ++nh){
      f32x4 acc1[2][2];
      #pragma unroll
      for (int m = 0; m < 2; ++m)
        #pragma unroll
        for (int nn = 0; nn < 2; ++nn) acc1[m][nn] = (f32x4)(0.f);
      #pragma unroll
      for (int kt = 0; kt < 4; ++kt){
        bf16x8 a[2], bb[2];
        #pragma unroll
        for (int m = 0; m < 2; ++m) a[m] = wf1f[((q*8 + w*2 + m)*4 + kt)*128 + l];
        #pragma unroll
        for (int nn = 0; nn < 2; ++nn){
          int p = (nh * 2 + nn) * 16 + ln;
          bb[nn] = *(const bf16x8*)(smem + p * 256 + (((kt*4 + lg) ^ (p & 7)) << 4));
        }
        #pragma unroll
        for (int m = 0; m < 2; ++m)
          #pragma unroll
          for (int nn = 0; nn < 2; ++nn)
            acc1[m][nn] = __builtin_amdgcn_mfma_f32_16x16x32_bf16(a[m], bb[nn], acc1[m][nn], 0, 0, 0);
      }
      #pragma unroll
      for (int m = 0; m < 2; ++m){
        int hrel = w * 32 + m * 16 + 4 * lg;
        int habs = q * 128 + hrel;
        f32x4 b1v = *(const f32x4*)(b1 + habs);
        int g8 = (hrel >> 3) ;
        #pragma unroll
        for (int nn = 0; nn < 2; ++nn){
          int p = (nh * 2 + nn) * 16 + ln;
          float v0 = gelu_tanh(acc1[m][nn][0] + b1v[0]);
          float v1 = gelu_tanh(acc1[m][nn][1] + b1v[1]);
          float v2 = gelu_tanh(acc1[m][nn][2] + b1v[2]);
          float v3 = gelu_tanh(acc1[m][nn][3] + b1v[3]);
          u32x2 pk; pk[0] = pkbf(v0, v1); pk[1] = pkbf(v2, v3);
          *(u32x2*)(smem + 16384 + p * 256 + ((g8 ^ (p & 7)) << 4) + ((lg & 1) << 3)) = pk;
        }
      }
    }
    __syncthreads();
    // W2 partial (k-tiles q*4..q*4+3)
    #pragma unroll
    for (int kt = 0; kt < 4; ++kt){
      bf16x8 a[2], bb[4];
      #pragma unroll
      for (int m = 0; m < 2; ++m) a[m] = wf2f[((w*2 + m)*16 + q*4 + kt)*128 + l];
      #pragma unroll
      for (int n = 0; n < 4; ++n){
        int p = n * 16 + ln;
        bb[n] = *(const bf16x8*)(smem + 16384 + p * 256 + (((kt*4 + lg) ^ (p & 7)) << 4));
      }
      #pragma unroll
      for (int m = 0; m < 2; ++m)
        #pragma unroll
        for (int n = 0; n < 4; ++n)
          acc2[m][n] = __builtin_amdgcn_mfma_f32_16x16x32_bf16(a[m], bb[n], acc2[m][n], 0, 0, 0);
    }
    __syncthreads();
  }
  // ---- epilogue: out = y (regs) + mlp + b2
  #pragma unroll
  for (int m = 0; m < 2; ++m){
    int o0 = w * 32 + m * 16 + 4 * lg;
    f32x4 b2v = *(const f32x4*)(b2 + o0);
    #pragma unroll
    for (int n = 0; n < 4; ++n){
      size_t base = ((size_t)(b * 128 + o0)) * HW + pix0 + n * 16 + ln;
      #pragma unroll
      for (int r = 0; r < 4; ++r)
        yout[base + (size_t)r * HW] = yv[m][n][r] + acc2[m][n][r] + b2v[r];
    }
  }
}

extern "C" void kernel_launch(void* const* d_in, const int* in_sizes, int n_in,
                              void* d_out, int out_size, void* d_ws, size_t ws_size,
                              hipStream_t stream)
{
  const float* x    = (const float*)d_in[0];
  const float* n1w  = (const float*)d_in[1];
  const float* n1b  = (const float*)d_in[2];
  const float* qkvw = (const float*)d_in[3];
  const float* qkvb = (const float*)d_in[4];
  const float* pw   = (const float*)d_in[5];
  const float* pb   = (const float*)d_in[6];
  const float* n2w  = (const float*)d_in[7];
  const float* n2b  = (const float*)d_in[8];
  const float* w1   = (const float*)d_in[9];
  const float* b1   = (const float*)d_in[10];
  const float* w2   = (const float*)d_in[11];
  const float* b2   = (const float*)d_in[12];

  u16* qkvp = (u16*)d_ws;                  // q/k/v planes, each [b][4][65536][32] = 128 MB
  u16* qbuf = qkvp;                        // q plane doubles as attention output
  u16* kbuf = qkvp + 67108864ull;
  u16* vbuf = qkvp + 134217728ull;
  u16* wf   = qkvp + 201326592ull;         // packed weights (768 KB)
  u16* wfq = wf;
  u16* wfp = wf + 98304;
  u16* wf1 = wf + 131072;
  u16* wf2 = wf + 262144;
  float* y = (float*)d_out;

  k_pack<<<384, 256, 0, stream>>>(qkvw, pw, w1, w2, wf);
  k_ln_qkv<<<8192, 256, 0, stream>>>(x, n1w, n1b, wfq, qkvb, qkvp);
  k_attn<<<8192, 256, 0, stream>>>(qbuf, kbuf, vbuf);
  k_proj_mlp<<<8192, 256, 0, stream>>>(qbuf, wfp, pb, x, n2w, n2b, wf1, b1, wf2, b2, y);
}